// Round 8
// baseline (306.500 us; speedup 1.0000x reference)
//
#include <hip/hip_runtime.h>
#include <hip/hip_bf16.h>
#include <math.h>

// FLASH (GAU-style) fused block. Round 7: 128x256 tiles (wave 64x128, 43 FLOP
// per LDS byte) for the big GEMMs; v-half computed transposed as its own GEMM
// (no transpose epilogue). qk/sim/kv keep the R6 128x128 path.
// b=4, n=4096, dim=512, hid=1024, qk=128, group=256.

#define BATCH 4
#define SEQ   4096
#define TROWS 16384      // BATCH*SEQ
#define DIMD  512
#define HIDD  1024
#define QKD   128
#define GRP   256
#define NGRP  16         // SEQ/GRP
#define BGRP  64         // BATCH*NGRP
#define EPIW  132        // padded LDS epilogue row stride (f32, 128-wide path)
#define EP2W  260        // padded LDS epilogue row stride (f32, 256-wide path)

typedef unsigned short bfraw;
typedef __attribute__((ext_vector_type(8))) short bf16x8;
typedef __attribute__((ext_vector_type(8))) unsigned short u16x8;
typedef __attribute__((ext_vector_type(4))) unsigned int u32x4;
typedef __attribute__((ext_vector_type(4))) float f32x4;

__device__ __forceinline__ float bf2f(bfraw u) {
    union { float f; unsigned int i; } c;
    c.i = ((unsigned int)u) << 16;
    return c.f;
}
__device__ __forceinline__ bfraw f2bf(float f) {
    unsigned int x = __float_as_uint(f);
    unsigned int r = (x + 0x7fffu + ((x >> 16) & 1u)) >> 16;   // RNE
    return (bfraw)r;
}
__device__ __forceinline__ unsigned int pkbf(float lo, float hi) {
    __hip_bfloat162 h2 = __float22bfloat162_rn(make_float2(lo, hi));
    union { __hip_bfloat162 h; unsigned int u; } c; c.h = h2;
    return c.u;
}
// 16 contiguous f32 -> 16 bf16 at dst (two 16B stores), packed cvt.
__device__ __forceinline__ void store16bf(bfraw* dst, const float* src) {
    u32x4 a, b;
    #pragma unroll
    for (int k = 0; k < 4; ++k) a[k] = pkbf(src[2 * k], src[2 * k + 1]);
    #pragma unroll
    for (int k = 0; k < 4; ++k) b[k] = pkbf(src[8 + 2 * k], src[8 + 2 * k + 1]);
    *(u32x4*)dst = a;
    *(u32x4*)(dst + 8) = b;
}
__device__ __forceinline__ float silu_f(float z) {
    return z / (1.f + __expf(-z));
}
__device__ __forceinline__ void gload_lds16(const void* g, void* l) {
    __builtin_amdgcn_global_load_lds(
        (const __attribute__((address_space(1))) unsigned int*)g,
        (__attribute__((address_space(3))) unsigned int*)l, 16, 0, 0);
}

// ======================= 128x128 path (qk/sim/kv) =======================
__device__ __forceinline__ void mfma_step(const bfraw* As, const bfraw* Bs,
                                          f32x4 acc[4][4], int wm, int wn,
                                          int q, int mi) {
    bf16x8 af[4], bfg[4];
    #pragma unroll
    for (int i = 0; i < 4; ++i)
        af[i] = *(const bf16x8*)&As[(size_t)(wm * 64 + i * 16 + mi) * 32 + q * 8];
    #pragma unroll
    for (int j = 0; j < 4; ++j)
        bfg[j] = *(const bf16x8*)&Bs[(size_t)(wn * 64 + j * 16 + mi) * 32 + q * 8];
    #pragma unroll
    for (int i = 0; i < 4; ++i)
        #pragma unroll
        for (int j = 0; j < 4; ++j)
            acc[i][j] = __builtin_amdgcn_mfma_f32_16x16x32_bf16(af[i], bfg[j], acc[i][j], 0, 0, 0);
}

#define SMEM_DECL(sz)                                           \
    __shared__ __align__(16) char smem_[sz];                    \
    bfraw* As0 = (bfraw*)smem_;                                 \
    bfraw* As1 = (bfraw*)(smem_ + 8192);                        \
    bfraw* Bs0 = (bfraw*)(smem_ + 16384);                       \
    bfraw* Bs1 = (bfraw*)(smem_ + 24576);

#define KLOOP_PRE(Abase, Astr, Bbase, Bstr)                                    \
    const bfraw* pa0 = (Abase) + (size_t)(t >> 2) * (Astr) + (t & 3) * 8;      \
    const bfraw* pa1 = pa0 + (size_t)64 * (Astr);                              \
    const bfraw* pb0 = (Bbase) + (size_t)(t >> 2) * (Bstr) + (t & 3) * 8;      \
    const bfraw* pb1 = pb0 + (size_t)64 * (Bstr);

#define LDS_DSTS                                                               \
    bfraw* lA0  = As0 + (size_t)wid * 512;                                     \
    bfraw* lA0b = As0 + 2048 + (size_t)wid * 512;                              \
    bfraw* lA1  = As1 + (size_t)wid * 512;                                     \
    bfraw* lA1b = As1 + 2048 + (size_t)wid * 512;                              \
    bfraw* lB0  = Bs0 + (size_t)wid * 512;                                     \
    bfraw* lB0b = Bs0 + 2048 + (size_t)wid * 512;                              \
    bfraw* lB1  = Bs1 + (size_t)wid * 512;                                     \
    bfraw* lB1b = Bs1 + 2048 + (size_t)wid * 512;

#define KSTEP64P                                                               \
    do {                                                                       \
        gload_lds16(pa0,      lA0);                                            \
        gload_lds16(pa1,      lA0b);                                           \
        gload_lds16(pa0 + 32, lA1);                                            \
        gload_lds16(pa1 + 32, lA1b);                                           \
        gload_lds16(pb0,      lB0);                                            \
        gload_lds16(pb1,      lB0b);                                           \
        gload_lds16(pb0 + 32, lB1);                                            \
        gload_lds16(pb1 + 32, lB1b);                                           \
        __syncthreads();                                                       \
        mfma_step(As0, Bs0, acc, wm, wn, q, mi);                               \
        mfma_step(As1, Bs1, acc, wm, wn, q, mi);                               \
        __syncthreads();                                                       \
        pa0 += 64; pa1 += 64; pb0 += 64; pb1 += 64;                            \
    } while (0)

__device__ __forceinline__ int epi_row(int p, int lr) {
    return (lr < 16) ? (p * 16 + lr) : (64 + p * 16 + (lr - 16));
}

// ======================= 128x256 path (big GEMMs) =======================
// Wave w: rows (w&1)*64, cols (w>>1)*128 of the 128x256 tile. acc 4x8.
__device__ __forceinline__ void mfma_step256(const bfraw* As, const bfraw* Bs,
                                             f32x4 acc[4][8], int wr, int wc,
                                             int q, int mi) {
    bf16x8 af[4], bfg[8];
    #pragma unroll
    for (int i = 0; i < 4; ++i)
        af[i] = *(const bf16x8*)&As[(size_t)(wr * 64 + i * 16 + mi) * 32 + q * 8];
    #pragma unroll
    for (int j = 0; j < 8; ++j)
        bfg[j] = *(const bf16x8*)&Bs[(size_t)(wc * 128 + j * 16 + mi) * 32 + q * 8];
    #pragma unroll
    for (int i = 0; i < 4; ++i)
        #pragma unroll
        for (int j = 0; j < 8; ++j)
            acc[i][j] = __builtin_amdgcn_mfma_f32_16x16x32_bf16(af[i], bfg[j], acc[i][j], 0, 0, 0);
}

#define SMEM256_DECL                                            \
    __shared__ __align__(16) char smem_[49152];                 \
    bfraw* As0 = (bfraw*)smem_;                                 \
    bfraw* As1 = (bfraw*)(smem_ + 8192);                        \
    bfraw* Bs0 = (bfraw*)(smem_ + 16384);                       \
    bfraw* Bs1 = (bfraw*)(smem_ + 32768);

#define KPRE256(Abase, Astr, Bbase, Bstr)                                      \
    const bfraw* pa0 = (Abase) + (size_t)(t >> 2) * (Astr) + (t & 3) * 8;      \
    const bfraw* pa1 = pa0 + (size_t)64 * (Astr);                              \
    const bfraw* pb0 = (Bbase) + (size_t)(t >> 2) * (Bstr) + (t & 3) * 8;      \
    const bfraw* pb1 = pb0 + (size_t)64 * (Bstr);                              \
    const bfraw* pb2 = pb0 + (size_t)128 * (Bstr);                             \
    const bfraw* pb3 = pb0 + (size_t)192 * (Bstr);

#define LDS256_DSTS                                                            \
    bfraw* lA0  = As0 + (size_t)wid * 512;                                     \
    bfraw* lA0b = As0 + 2048 + (size_t)wid * 512;                              \
    bfraw* lA1  = As1 + (size_t)wid * 512;                                     \
    bfraw* lA1b = As1 + 2048 + (size_t)wid * 512;                              \
    bfraw* lB00 = Bs0 + (size_t)wid * 512;                                     \
    bfraw* lB01 = Bs0 + 2048 + (size_t)wid * 512;                              \
    bfraw* lB02 = Bs0 + 4096 + (size_t)wid * 512;                              \
    bfraw* lB03 = Bs0 + 6144 + (size_t)wid * 512;                              \
    bfraw* lB10 = Bs1 + (size_t)wid * 512;                                     \
    bfraw* lB11 = Bs1 + 2048 + (size_t)wid * 512;                              \
    bfraw* lB12 = Bs1 + 4096 + (size_t)wid * 512;                              \
    bfraw* lB13 = Bs1 + 6144 + (size_t)wid * 512;

#define KSTEP64W                                                               \
    do {                                                                       \
        gload_lds16(pa0,      lA0);                                            \
        gload_lds16(pa1,      lA0b);                                           \
        gload_lds16(pa0 + 32, lA1);                                            \
        gload_lds16(pa1 + 32, lA1b);                                           \
        gload_lds16(pb0,      lB00);                                           \
        gload_lds16(pb1,      lB01);                                           \
        gload_lds16(pb2,      lB02);                                           \
        gload_lds16(pb3,      lB03);                                           \
        gload_lds16(pb0 + 32, lB10);                                           \
        gload_lds16(pb1 + 32, lB11);                                           \
        gload_lds16(pb2 + 32, lB12);                                           \
        gload_lds16(pb3 + 32, lB13);                                           \
        __syncthreads();                                                       \
        mfma_step256(As0, Bs0, acc, wr, wc, q, mi);                            \
        mfma_step256(As1, Bs1, acc, wr, wc, q, mi);                            \
        __syncthreads();                                                       \
        pa0 += 64; pa1 += 64; pb0 += 64; pb1 += 64; pb2 += 64; pb3 += 64;      \
    } while (0)

// ---------------- LayerNorm ----------------
__global__ __launch_bounds__(256) void ln_kernel(const float* __restrict__ x,
                                                 const float* __restrict__ w,
                                                 const float* __restrict__ b,
                                                 bfraw* __restrict__ outb) {
    int row  = blockIdx.x * 4 + (threadIdx.x >> 6);
    int lane = threadIdx.x & 63;
    const float* xr = x + (size_t)row * DIMD;
    float4 v0 = ((const float4*)xr)[lane];
    float4 v1 = ((const float4*)xr)[lane + 64];
    float s  = v0.x + v0.y + v0.z + v0.w + v1.x + v1.y + v1.z + v1.w;
    float ss = v0.x*v0.x + v0.y*v0.y + v0.z*v0.z + v0.w*v0.w
             + v1.x*v1.x + v1.y*v1.y + v1.z*v1.z + v1.w*v1.w;
    #pragma unroll
    for (int off = 32; off; off >>= 1) {
        s  += __shfl_xor(s, off);
        ss += __shfl_xor(ss, off);
    }
    float mu  = s * (1.f / DIMD);
    float var = ss * (1.f / DIMD) - mu * mu;
    float inv = rsqrtf(var + 1e-5f);
    float4 w0 = ((const float4*)w)[lane],  w1 = ((const float4*)w)[lane + 64];
    float4 b0 = ((const float4*)b)[lane],  b1 = ((const float4*)b)[lane + 64];
    unsigned int o0 = pkbf((v0.x - mu) * inv * w0.x + b0.x,
                           (v0.y - mu) * inv * w0.y + b0.y);
    unsigned int o1 = pkbf((v0.z - mu) * inv * w0.z + b0.z,
                           (v0.w - mu) * inv * w0.w + b0.w);
    unsigned int o2 = pkbf((v1.x - mu) * inv * w1.x + b1.x,
                           (v1.y - mu) * inv * w1.y + b1.y);
    unsigned int o3 = pkbf((v1.z - mu) * inv * w1.z + b1.z,
                           (v1.w - mu) * inv * w1.w + b1.w);
    unsigned int* brow = (unsigned int*)(outb + (size_t)row * DIMD);
    ((uint2*)brow)[lane]      = make_uint2(o0, o1);
    ((uint2*)brow)[lane + 64] = make_uint2(o2, o3);
}

// ------------- transpose + convert: fp32 [R][C] -> bf16 [C][R] -------------
__global__ __launch_bounds__(256) void transpose_f32_bf16(const float* __restrict__ in,
                                                          bfraw* __restrict__ outp,
                                                          int R, int C) {
    __shared__ float tile[32][33];
    int c0 = blockIdx.x * 32, r0 = blockIdx.y * 32;
    int t = threadIdx.x;
    int tr = t >> 3, tc4 = (t & 7) * 4;
    float4 v = *(const float4*)&in[(size_t)(r0 + tr) * C + c0 + tc4];
    tile[tr][tc4 + 0] = v.x; tile[tr][tc4 + 1] = v.y;
    tile[tr][tc4 + 2] = v.z; tile[tr][tc4 + 3] = v.w;
    __syncthreads();
    ushort4 s;
    s.x = f2bf(tile[tc4 + 0][tr]);
    s.y = f2bf(tile[tc4 + 1][tr]);
    s.z = f2bf(tile[tc4 + 2][tr]);
    s.w = f2bf(tile[tc4 + 3][tr]);
    *(ushort4*)&outp[(size_t)(c0 + tr) * R + r0 + tc4] = s;
}

// ------------- gemm_vT: vT[bg][e][j] = silu(WhT_v[e] . normb[bg*256+j] + bh[e]) -------------
// grid (1, HIDD/128, BGRP). 128x256 tile: rows = e, cols = j (whole group).
__global__ __launch_bounds__(256, 2) void gemm_vT(const bfraw* __restrict__ WhTv,
                                                  const bfraw* __restrict__ normb,
                                                  const float* __restrict__ bias,
                                                  bfraw* __restrict__ vT) {
    SMEM256_DECL
    float* epi = (float*)smem_;
    int t = threadIdx.x;
    int lane = t & 63, wid = t >> 6;
    int wr = wid & 1, wc = wid >> 1;
    int q = lane >> 4, mi = lane & 15;
    int row0 = blockIdx.y * 128;
    int bg = blockIdx.z;
    f32x4 acc[4][8] = {};
    LDS256_DSTS
    {
        KPRE256(WhTv + (size_t)row0 * DIMD, DIMD,
                normb + (size_t)bg * GRP * DIMD, DIMD)
        #pragma unroll
        for (int k0 = 0; k0 < DIMD; k0 += 64) KSTEP64W;
    }
    bfraw* outg = vT + (size_t)bg * HIDD * GRP;
    #pragma unroll
    for (int p = 0; p < 4; ++p) {
        #pragma unroll
        for (int rg = 0; rg < 4; ++rg) {
            float bv = bias[row0 + wr * 64 + p * 16 + q * 4 + rg];
            #pragma unroll
            for (int j = 0; j < 8; ++j)
                epi[(wr * 16 + q * 4 + rg) * EP2W + wc * 128 + j * 16 + mi] =
                    silu_f(acc[p][j][rg] + bv);
        }
        __syncthreads();
        int lr = t >> 3;
        int gr = row0 + epi_row(p, lr);
        #pragma unroll
        for (int half = 0; half < 2; ++half) {
            int c0t = (t & 7) * 16 + half * 128;
            store16bf(outg + (size_t)gr * GRP + c0t, &epi[lr * EP2W + c0t]);
        }
        __syncthreads();
    }
}

// ------------- gemm_gate: gate[r][e] = silu(normb[r] . WhT_g[e] + bh[1024+e]) -------------
// grid (HIDD/256, TROWS/128). 128x256.
__global__ __launch_bounds__(256, 2) void gemm_gate(const bfraw* __restrict__ A,
                                                    const bfraw* __restrict__ BT,
                                                    const float* __restrict__ bias,
                                                    bfraw* __restrict__ gate) {
    SMEM256_DECL
    float* epi = (float*)smem_;
    int t = threadIdx.x;
    int lane = t & 63, wid = t >> 6;
    int wr = wid & 1, wc = wid >> 1;
    int q = lane >> 4, mi = lane & 15;
    int row0 = blockIdx.y * 128, col0 = blockIdx.x * 256;
    f32x4 acc[4][8] = {};
    LDS256_DSTS
    {
        KPRE256(A + (size_t)row0 * DIMD, DIMD, BT + (size_t)col0 * DIMD, DIMD)
        #pragma unroll
        for (int k0 = 0; k0 < DIMD; k0 += 64) KSTEP64W;
    }
    #pragma unroll
    for (int p = 0; p < 4; ++p) {
        #pragma unroll
        for (int j = 0; j < 8; ++j) {
            float bv = bias[col0 + wc * 128 + j * 16 + mi];
            #pragma unroll
            for (int rg = 0; rg < 4; ++rg)
                epi[(wr * 16 + q * 4 + rg) * EP2W + wc * 128 + j * 16 + mi] =
                    silu_f(acc[p][j][rg] + bv);
        }
        __syncthreads();
        int lr = t >> 3;
        int gr = row0 + epi_row(p, lr);
        #pragma unroll
        for (int half = 0; half < 2; ++half) {
            int c0t = (t & 7) * 16 + half * 128;
            store16bf(gate + (size_t)gr * HIDD + col0 + c0t, &epi[lr * EP2W + c0t]);
        }
        __syncthreads();
    }
}

// ------------- qk GEMM (128x128): emit qq/lq/kk row-major + lkT -------------
__global__ __launch_bounds__(256) void qk_mfma(const bfraw* __restrict__ A,
                                               const bfraw* __restrict__ BT,
                                               const float* __restrict__ bqk,
                                               const float* __restrict__ gamma,
                                               const float* __restrict__ beta,
                                               bfraw* __restrict__ qq,
                                               bfraw* __restrict__ lq,
                                               bfraw* __restrict__ kk,
                                               bfraw* __restrict__ lkT) {
    SMEM_DECL(32768)
    float* epi = (float*)smem_;
    int t = threadIdx.x;
    int lane = t & 63, wid = t >> 6;
    int wm = wid >> 1, wn = wid & 1;
    int q = lane >> 4, mi = lane & 15;
    int row0 = blockIdx.y * 128;
    f32x4 acc[4][4] = {};
    LDS_DSTS
    {
        KLOOP_PRE(A + (size_t)row0 * DIMD, DIMD, BT, DIMD)
        #pragma unroll
        for (int k0 = 0; k0 < DIMD; k0 += 64) KSTEP64P;
    }
    int bg = row0 >> 8;
    #pragma unroll
    for (int p = 0; p < 4; ++p) {
        #pragma unroll
        for (int j = 0; j < 4; ++j) {
            float bv = bqk[wn * 64 + j * 16 + mi];
            #pragma unroll
            for (int rg = 0; rg < 4; ++rg)
                epi[(wm * 16 + q * 4 + rg) * EPIW + wn * 64 + j * 16 + mi] =
                    silu_f(acc[p][j][rg] + bv);
        }
        __syncthreads();
        {
            int lr = t >> 3, c0t = (t & 7) * 16;
            int gr = row0 + epi_row(p, lr);
            const float* src = &epi[lr * EPIW + c0t];
            float z[16];
            #pragma unroll
            for (int k = 0; k < 16; ++k) z[k] = src[k];
            #pragma unroll
            for (int hd = 0; hd < 3; ++hd) {        // 0:qq 1:lq 2:kk
                bfraw* arr = (hd == 0) ? qq : (hd == 1) ? lq : kk;
                const float* gp = gamma + hd * QKD + c0t;
                const float* ep = beta  + hd * QKD + c0t;
                float tmp[16];
                #pragma unroll
                for (int k = 0; k < 16; ++k) tmp[k] = z[k] * gp[k] + ep[k];
                store16bf(arr + (size_t)gr * QKD + c0t, tmp);
            }
        }
        {
            int c = t >> 1, half = t & 1;
            float g3 = gamma[3 * QKD + c], e3 = beta[3 * QKD + c];
            int j0 = (row0 & 255) + half * 64 + p * 16;
            float tmp[16];
            #pragma unroll
            for (int k = 0; k < 16; ++k)
                tmp[k] = epi[(half * 16 + k) * EPIW + c] * g3 + e3;
            store16bf(lkT + ((size_t)bg * QKD + c) * GRP + j0, tmp);
        }
        __syncthreads();
    }
}

// ------------- sim (128x128): attn = mask(relu(qq.kk/G)^2) -------------
__global__ __launch_bounds__(256) void sim_mfma(const bfraw* __restrict__ qq,
                                                const bfraw* __restrict__ kk,
                                                bfraw* __restrict__ attn) {
    int bg = blockIdx.y;
    int tid = blockIdx.x;
    int ry = (tid == 0) ? 0 : 1;
    int rx = (tid == 2) ? 1 : 0;
    int row0 = ry * 128, col0 = rx * 128;
    SMEM_DECL(32768)
    float* epi = (float*)smem_;
    int t = threadIdx.x;
    int lane = t & 63, wid = t >> 6;
    int wm = wid >> 1, wn = wid & 1;
    int q = lane >> 4, mi = lane & 15;
    f32x4 acc[4][4] = {};
    LDS_DSTS
    {
        KLOOP_PRE(qq + (size_t)(bg * GRP + row0) * QKD, QKD,
                  kk + (size_t)(bg * GRP + col0) * QKD, QKD)
        #pragma unroll
        for (int k0 = 0; k0 < QKD; k0 += 64) KSTEP64P;
    }
    bfraw* ag = attn + (size_t)bg * GRP * GRP;
    #pragma unroll
    for (int p = 0; p < 4; ++p) {
        #pragma unroll
        for (int j = 0; j < 4; ++j) {
            int colg = col0 + wn * 64 + j * 16 + mi;
            #pragma unroll
            for (int rg = 0; rg < 4; ++rg) {
                int rowg = row0 + wm * 64 + p * 16 + q * 4 + rg;
                float s = acc[p][j][rg] * (1.f / GRP);
                s = fmaxf(s, 0.f);
                s = s * s;
                epi[(wm * 16 + q * 4 + rg) * EPIW + wn * 64 + j * 16 + mi] =
                    (colg > rowg) ? 0.f : s;
            }
        }
        __syncthreads();
        int lr = t >> 3, c0t = (t & 7) * 16;
        int gr = row0 + epi_row(p, lr);
        store16bf(ag + (size_t)gr * GRP + col0 + c0t, &epi[lr * EPIW + c0t]);
        __syncthreads();
    }
}

// ------------- kv (128x128): kvT_raw[bg][e][d] = sum_j vT[e][j]*lkT[d][j] -------------
__global__ __launch_bounds__(256) void kv_mfma(const bfraw* __restrict__ vT,
                                               const bfraw* __restrict__ lkT,
                                               bfraw* __restrict__ kvT_raw) {
    int bg = blockIdx.z;
    int row0 = blockIdx.y * 128;
    SMEM_DECL(32768)
    float* epi = (float*)smem_;
    int t = threadIdx.x;
    int lane = t & 63, wid = t >> 6;
    int wm = wid >> 1, wn = wid & 1;
    int q = lane >> 4, mi = lane & 15;
    f32x4 acc[4][4] = {};
    LDS_DSTS
    {
        KLOOP_PRE(vT + (size_t)bg * HIDD * GRP + (size_t)row0 * GRP, GRP,
                  lkT + (size_t)bg * QKD * GRP, GRP)
        #pragma unroll
        for (int k0 = 0; k0 < GRP; k0 += 64) KSTEP64P;
    }
    bfraw* outg = kvT_raw + (size_t)bg * HIDD * QKD;
    #pragma unroll
    for (int p = 0; p < 4; ++p) {
        #pragma unroll
        for (int j = 0; j < 4; ++j)
            #pragma unroll
            for (int rg = 0; rg < 4; ++rg)
                epi[(wm * 16 + q * 4 + rg) * EPIW + wn * 64 + j * 16 + mi] = acc[p][j][rg];
        __syncthreads();
        int lr = t >> 3, c0t = (t & 7) * 16;
        int gr = row0 + epi_row(p, lr);
        store16bf(outg + (size_t)gr * QKD + c0t, &epi[lr * EPIW + c0t]);
        __syncthreads();
    }
}

// ------------- exclusive cumsum over groups (with /G) -------------
__global__ __launch_bounds__(256) void cumsum2_kernel(const bfraw* __restrict__ raw,
                                                      bfraw* __restrict__ ex) {
    int idx = blockIdx.x * 256 + threadIdx.x;
    int b = idx >> 17;
    int r = idx & 131071;
    const bfraw* rp = raw + (size_t)b * NGRP * 131072 + r;
    bfraw* ep = ex + (size_t)b * NGRP * 131072 + r;
    float run = 0.f;
    #pragma unroll
    for (int g = 0; g < NGRP; ++g) {
        ep[(size_t)g * 131072] = f2bf(run);
        run += bf2f(rp[(size_t)g * 131072]) * (1.f / GRP);
    }
}

// ------------- quadlin (128x256): gated = gate .* (attn@vv + lq@kv_ex) -------------
// grid (HIDD/256, GRP/128, BGRP).
__global__ __launch_bounds__(256, 2) void quadlin_mfma(const bfraw* __restrict__ attn,
                                                       const bfraw* __restrict__ vT,
                                                       const bfraw* __restrict__ lq,
                                                       const bfraw* __restrict__ kvT_ex,
                                                       const bfraw* __restrict__ gate,
                                                       bfraw* __restrict__ gated) {
    int bg = blockIdx.z;
    int row0 = blockIdx.y * 128;
    int col0 = blockIdx.x * 256;
    SMEM256_DECL
    float* epi = (float*)smem_;
    int t = threadIdx.x;
    int lane = t & 63, wid = t >> 6;
    int wr = wid & 1, wc = wid >> 1;
    int q = lane >> 4, mi = lane & 15;
    f32x4 acc[4][8] = {};
    LDS256_DSTS
    // Part 1: quadratic. A = attn rows (stride 256), B = vT rows (stride 256).
    {
        KPRE256(attn + (size_t)bg * GRP * GRP + (size_t)row0 * GRP, GRP,
                vT + (size_t)bg * HIDD * GRP + (size_t)col0 * GRP, GRP)
        int kmax = row0 + 128;     // causal
        for (int k0 = 0; k0 < kmax; k0 += 64) KSTEP64W;
    }
    // Part 2: linear. A = lq (stride 128), B = kvT_ex rows (stride 128).
    {
        KPRE256(lq + (size_t)(bg * GRP + row0) * QKD, QKD,
                kvT_ex + (size_t)bg * HIDD * QKD + (size_t)col0 * QKD, QKD)
        #pragma unroll
        for (int k0 = 0; k0 < QKD; k0 += 64) KSTEP64W;
    }
    #pragma unroll
    for (int p = 0; p < 4; ++p) {
        #pragma unroll
        for (int j = 0; j < 8; ++j)
            #pragma unroll
            for (int rg = 0; rg < 4; ++rg)
                epi[(wr * 16 + q * 4 + rg) * EP2W + wc * 128 + j * 16 + mi] = acc[p][j][rg];
        __syncthreads();
        int lr = t >> 3;
        int gr = row0 + epi_row(p, lr);
        size_t grow = (size_t)bg * GRP + gr;
        #pragma unroll
        for (int half = 0; half < 2; ++half) {
            int c0t = (t & 7) * 16 + half * 128;
            const float* src = &epi[lr * EP2W + c0t];
            const bfraw* gsrc = gate + grow * HIDD + col0 + c0t;
            u16x8 g0 = *(const u16x8*)gsrc;
            u16x8 g1 = *(const u16x8*)(gsrc + 8);
            float tmp[16];
            #pragma unroll
            for (int k = 0; k < 8; ++k) tmp[k] = src[k] * bf2f(g0[k]);
            #pragma unroll
            for (int k = 0; k < 8; ++k) tmp[8 + k] = src[8 + k] * bf2f(g1[k]);
            store16bf(gated + grow * HIDD + col0 + c0t, tmp);
        }
        __syncthreads();
    }
}

// ------------- final (128x256): out = gated @ WoT^T + bo + x  (fp32) -------------
// grid (DIMD/256, TROWS/128).
__global__ __launch_bounds__(256, 2) void gemm_final(const bfraw* __restrict__ A,
                                                     const bfraw* __restrict__ BT,
                                                     const float* __restrict__ bo,
                                                     const float* __restrict__ x,
                                                     float* __restrict__ out) {
    SMEM256_DECL
    float* epi = (float*)smem_;
    int t = threadIdx.x;
    int lane = t & 63, wid = t >> 6;
    int wr = wid & 1, wc = wid >> 1;
    int q = lane >> 4, mi = lane & 15;
    int row0 = blockIdx.y * 128, col0 = blockIdx.x * 256;
    f32x4 acc[4][8] = {};
    LDS256_DSTS
    {
        KPRE256(A + (size_t)row0 * HIDD, HIDD, BT + (size_t)col0 * HIDD, HIDD)
        #pragma unroll
        for (int k0 = 0; k0 < HIDD; k0 += 64) KSTEP64W;
    }
    #pragma unroll
    for (int p = 0; p < 4; ++p) {
        #pragma unroll
        for (int j = 0; j < 8; ++j) {
            float bv = bo[col0 + wc * 128 + j * 16 + mi];
            #pragma unroll
            for (int rg = 0; rg < 4; ++rg)
                epi[(wr * 16 + q * 4 + rg) * EP2W + wc * 128 + j * 16 + mi] =
                    acc[p][j][rg] + bv;
        }
        __syncthreads();
        int lr = t >> 3;
        int gr = row0 + epi_row(p, lr);
        #pragma unroll
        for (int half = 0; half < 2; ++half) {
            int c0t = (t & 7) * 16 + half * 128;
            const float* src = &epi[lr * EP2W + c0t];
            const float* xsrc = x + (size_t)gr * DIMD + col0 + c0t;
            float* dst = out + (size_t)gr * DIMD + col0 + c0t;
            #pragma unroll
            for (int v = 0; v < 4; ++v) {
                float4 a = ((const float4*)src)[v];
                float4 xv = ((const float4*)xsrc)[v];
                a.x += xv.x; a.y += xv.y; a.z += xv.z; a.w += xv.w;
                ((float4*)dst)[v] = a;
            }
        }
        __syncthreads();
    }
}

extern "C" void kernel_launch(void* const* d_in, const int* in_sizes, int n_in,
                              void* d_out, int out_size, void* d_ws, size_t ws_size,
                              hipStream_t stream) {
    const float* x     = (const float*)d_in[0];
    const float* ln_w  = (const float*)d_in[1];
    const float* ln_b  = (const float*)d_in[2];
    const float* Wh    = (const float*)d_in[3];
    const float* bh    = (const float*)d_in[4];
    const float* Wqk   = (const float*)d_in[5];
    const float* bqk   = (const float*)d_in[6];
    const float* gamma = (const float*)d_in[7];
    const float* beta  = (const float*)d_in[8];
    const float* Wo    = (const float*)d_in[9];
    const float* bo    = (const float*)d_in[10];
    float* out = (float*)d_out;

    // d_out (32 MiB) hosts short-lived buffers; all dead before gemm_final writes out.
    char* outb_ = (char*)d_out;
    bfraw* attn = (bfraw*)(outb_);                    //  8 MiB [64][256][256]
    bfraw* qq   = (bfraw*)(outb_ + 8388608);          //  4 MiB [16384][128]
    bfraw* kk   = (bfraw*)(outb_ + 12582912);         //  4 MiB
    bfraw* lq   = (bfraw*)(outb_ + 16777216);         //  4 MiB
    bfraw* WhT  = (bfraw*)(outb_ + 20971520);         //  2 MiB [2048][512]
    bfraw* WqkT = (bfraw*)(outb_ + 23068672);         //  128 KiB [128][512]

    // ws layout (byte offsets):
    char* wsb = (char*)d_ws;
    bfraw* vT      = (bfraw*)(wsb);                   // 32 MiB [64][1024][256]
    bfraw* gate    = (bfraw*)(wsb + 33554432);        // 32 MiB [16384][1024]
    bfraw* gated   = (bfraw*)(wsb + 67108864);        // 32 MiB [16384][1024]
    bfraw* normb   = (bfraw*)(wsb + 100663296);       // 16 MiB [16384][512]
    bfraw* kvT_raw = (bfraw*)(wsb + 117440512);       // 16 MiB [64][1024][128]
    bfraw* kvT_ex  = (bfraw*)(wsb + 134217728);       // 16 MiB [64][1024][128]
    bfraw* lkT     = (bfraw*)(wsb + 150994944);       //  4 MiB [64][128][256]
    bfraw* WoT     = (bfraw*)(wsb + 155189248);       //  1 MiB [512][1024]

    // 0-2. weight transposes to bf16 [N][K]
    transpose_f32_bf16<<<dim3(2 * HIDD / 32, DIMD / 32), 256, 0, stream>>>(Wh, WhT, DIMD, 2 * HIDD);
    transpose_f32_bf16<<<dim3(DIMD / 32, HIDD / 32), 256, 0, stream>>>(Wo, WoT, HIDD, DIMD);
    transpose_f32_bf16<<<dim3(QKD / 32, DIMD / 32), 256, 0, stream>>>(Wqk, WqkT, DIMD, QKD);
    // 3. LayerNorm -> normb bf16
    ln_kernel<<<TROWS / 4, 256, 0, stream>>>(x, ln_w, ln_b, normb);
    // 4a. vT[bg][e][j] = silu(WhT_v[e].normb[bg*256+j] + bh[e])  — transposed orientation
    gemm_vT<<<dim3(1, HIDD / 128, BGRP), 256, 0, stream>>>(WhT, normb, bh, vT);
    // 4b. gate = silu(normb @ Wh_gate + bh_gate) row-major
    gemm_gate<<<dim3(HIDD / 256, TROWS / 128), 256, 0, stream>>>(
        normb, WhT + (size_t)HIDD * DIMD, bh + HIDD, gate);
    // 5. qk heads -> qq/lq/kk row-major + lkT transposed
    qk_mfma<<<dim3(1, TROWS / 128), 256, 0, stream>>>(normb, WqkT, bqk, gamma, beta, qq, lq, kk, lkT);
    // 6. attn = mask(relu(qq @ kk^T / G)^2)
    sim_mfma<<<dim3(3, BGRP), 256, 0, stream>>>(qq, kk, attn);
    // 7. kvT_raw[e][d] = sum_j vT[e][j]*lkT[d][j]
    kv_mfma<<<dim3(1, HIDD / 128, BGRP), 256, 0, stream>>>(vT, lkT, kvT_raw);
    // 8. exclusive cumsum over groups (with /G) -> kvT_ex
    cumsum2_kernel<<<(BATCH * QKD * HIDD) / 256, 256, 0, stream>>>(kvT_raw, kvT_ex);
    // 9. gated = gate .* (attn@vv + lq@kv_ex)
    quadlin_mfma<<<dim3(HIDD / 256, GRP / 128, BGRP), 256, 0, stream>>>(
        attn, vT, lq, kvT_ex, gate, gated);
    // 10. out = gated @ Wo + bo + x
    gemm_final<<<dim3(DIMD / 256, TROWS / 128), 256, 0, stream>>>(gated, WoT, bo, x, out);
}

// Round 9
// 294.975 us; speedup vs baseline: 1.0391x; 1.0391x over previous
//
#include <hip/hip_runtime.h>
#include <hip/hip_bf16.h>
#include <math.h>

// FLASH (GAU-style) fused block. Round 8: revert to R6 128x128 structure
// (>=2 blocks/CU everywhere — R7's 256-wide tiles dropped final to 1 block/CU
// and regressed); qk GEMM merged into gemm_h as a 17th column tile.
// b=4, n=4096, dim=512, hid=1024, qk=128, group=256.

#define BATCH 4
#define SEQ   4096
#define TROWS 16384      // BATCH*SEQ
#define DIMD  512
#define HIDD  1024
#define QKD   128
#define GRP   256
#define NGRP  16         // SEQ/GRP
#define BGRP  64         // BATCH*NGRP
#define EPIW  132        // padded LDS epilogue row stride (f32 path)
#define EPB   130        // bf16 full-tile epilogue row stride (shorts)

typedef unsigned short bfraw;
typedef __attribute__((ext_vector_type(8))) short bf16x8;
typedef __attribute__((ext_vector_type(8))) unsigned short u16x8;
typedef __attribute__((ext_vector_type(4))) unsigned int u32x4;
typedef __attribute__((ext_vector_type(4))) float f32x4;

__device__ __forceinline__ float bf2f(bfraw u) {
    union { float f; unsigned int i; } c;
    c.i = ((unsigned int)u) << 16;
    return c.f;
}
__device__ __forceinline__ bfraw f2bf(float f) {
    unsigned int x = __float_as_uint(f);
    unsigned int r = (x + 0x7fffu + ((x >> 16) & 1u)) >> 16;   // RNE
    return (bfraw)r;
}
__device__ __forceinline__ unsigned int pkbf(float lo, float hi) {
    __hip_bfloat162 h2 = __float22bfloat162_rn(make_float2(lo, hi));
    union { __hip_bfloat162 h; unsigned int u; } c; c.h = h2;
    return c.u;
}
// 16 contiguous f32 -> 16 bf16 at dst (two 16B stores), packed cvt.
__device__ __forceinline__ void store16bf(bfraw* dst, const float* src) {
    u32x4 a, b;
    #pragma unroll
    for (int k = 0; k < 4; ++k) a[k] = pkbf(src[2 * k], src[2 * k + 1]);
    #pragma unroll
    for (int k = 0; k < 4; ++k) b[k] = pkbf(src[8 + 2 * k], src[8 + 2 * k + 1]);
    *(u32x4*)dst = a;
    *(u32x4*)(dst + 8) = b;
}
__device__ __forceinline__ float silu_f(float z) {
    return z / (1.f + __expf(-z));
}
__device__ __forceinline__ void gload_lds16(const void* g, void* l) {
    __builtin_amdgcn_global_load_lds(
        (const __attribute__((address_space(1))) unsigned int*)g,
        (__attribute__((address_space(3))) unsigned int*)l, 16, 0, 0);
}

// One BK=32 MFMA step on staged tiles (4 waves, each 64x64 = 4x4 frags).
__device__ __forceinline__ void mfma_step(const bfraw* As, const bfraw* Bs,
                                          f32x4 acc[4][4], int wm, int wn,
                                          int q, int mi) {
    bf16x8 af[4], bfg[4];
    #pragma unroll
    for (int i = 0; i < 4; ++i)
        af[i] = *(const bf16x8*)&As[(size_t)(wm * 64 + i * 16 + mi) * 32 + q * 8];
    #pragma unroll
    for (int j = 0; j < 4; ++j)
        bfg[j] = *(const bf16x8*)&Bs[(size_t)(wn * 64 + j * 16 + mi) * 32 + q * 8];
    #pragma unroll
    for (int i = 0; i < 4; ++i)
        #pragma unroll
        for (int j = 0; j < 4; ++j)
            acc[i][j] = __builtin_amdgcn_mfma_f32_16x16x32_bf16(af[i], bfg[j], acc[i][j], 0, 0, 0);
}

#define SMEM_DECL(sz)                                           \
    __shared__ __align__(16) char smem_[sz];                    \
    bfraw* As0 = (bfraw*)smem_;                                 \
    bfraw* As1 = (bfraw*)(smem_ + 8192);                        \
    bfraw* Bs0 = (bfraw*)(smem_ + 16384);                       \
    bfraw* Bs1 = (bfraw*)(smem_ + 24576);

#define KLOOP_PRE(Abase, Astr, Bbase, Bstr)                                    \
    const bfraw* pa0 = (Abase) + (size_t)(t >> 2) * (Astr) + (t & 3) * 8;      \
    const bfraw* pa1 = pa0 + (size_t)64 * (Astr);                              \
    const bfraw* pb0 = (Bbase) + (size_t)(t >> 2) * (Bstr) + (t & 3) * 8;      \
    const bfraw* pb1 = pb0 + (size_t)64 * (Bstr);

#define LDS_DSTS                                                               \
    bfraw* lA0  = As0 + (size_t)wid * 512;                                     \
    bfraw* lA0b = As0 + 2048 + (size_t)wid * 512;                              \
    bfraw* lA1  = As1 + (size_t)wid * 512;                                     \
    bfraw* lA1b = As1 + 2048 + (size_t)wid * 512;                              \
    bfraw* lB0  = Bs0 + (size_t)wid * 512;                                     \
    bfraw* lB0b = Bs0 + 2048 + (size_t)wid * 512;                              \
    bfraw* lB1  = Bs1 + (size_t)wid * 512;                                     \
    bfraw* lB1b = Bs1 + 2048 + (size_t)wid * 512;

#define KSTEP64P                                                               \
    do {                                                                       \
        gload_lds16(pa0,      lA0);                                            \
        gload_lds16(pa1,      lA0b);                                           \
        gload_lds16(pa0 + 32, lA1);                                            \
        gload_lds16(pa1 + 32, lA1b);                                           \
        gload_lds16(pb0,      lB0);                                            \
        gload_lds16(pb1,      lB0b);                                           \
        gload_lds16(pb0 + 32, lB1);                                            \
        gload_lds16(pb1 + 32, lB1b);                                           \
        __syncthreads();                                                       \
        mfma_step(As0, Bs0, acc, wm, wn, q, mi);                               \
        mfma_step(As1, Bs1, acc, wm, wn, q, mi);                               \
        __syncthreads();                                                       \
        pa0 += 64; pa1 += 64; pb0 += 64; pb1 += 64;                            \
    } while (0)

__device__ __forceinline__ int epi_row(int p, int lr) {
    return (lr < 16) ? (p * 16 + lr) : (64 + p * 16 + (lr - 16));
}

// ---------------- LayerNorm ----------------
__global__ __launch_bounds__(256) void ln_kernel(const float* __restrict__ x,
                                                 const float* __restrict__ w,
                                                 const float* __restrict__ b,
                                                 bfraw* __restrict__ outb) {
    int row  = blockIdx.x * 4 + (threadIdx.x >> 6);
    int lane = threadIdx.x & 63;
    const float* xr = x + (size_t)row * DIMD;
    float4 v0 = ((const float4*)xr)[lane];
    float4 v1 = ((const float4*)xr)[lane + 64];
    float s  = v0.x + v0.y + v0.z + v0.w + v1.x + v1.y + v1.z + v1.w;
    float ss = v0.x*v0.x + v0.y*v0.y + v0.z*v0.z + v0.w*v0.w
             + v1.x*v1.x + v1.y*v1.y + v1.z*v1.z + v1.w*v1.w;
    #pragma unroll
    for (int off = 32; off; off >>= 1) {
        s  += __shfl_xor(s, off);
        ss += __shfl_xor(ss, off);
    }
    float mu  = s * (1.f / DIMD);
    float var = ss * (1.f / DIMD) - mu * mu;
    float inv = rsqrtf(var + 1e-5f);
    float4 w0 = ((const float4*)w)[lane],  w1 = ((const float4*)w)[lane + 64];
    float4 b0 = ((const float4*)b)[lane],  b1 = ((const float4*)b)[lane + 64];
    unsigned int o0 = pkbf((v0.x - mu) * inv * w0.x + b0.x,
                           (v0.y - mu) * inv * w0.y + b0.y);
    unsigned int o1 = pkbf((v0.z - mu) * inv * w0.z + b0.z,
                           (v0.w - mu) * inv * w0.w + b0.w);
    unsigned int o2 = pkbf((v1.x - mu) * inv * w1.x + b1.x,
                           (v1.y - mu) * inv * w1.y + b1.y);
    unsigned int o3 = pkbf((v1.z - mu) * inv * w1.z + b1.z,
                           (v1.w - mu) * inv * w1.w + b1.w);
    unsigned int* brow = (unsigned int*)(outb + (size_t)row * DIMD);
    ((uint2*)brow)[lane]      = make_uint2(o0, o1);
    ((uint2*)brow)[lane + 64] = make_uint2(o2, o3);
}

// ------------- transpose + convert: fp32 [R][C] -> bf16 [C][R] -------------
__global__ __launch_bounds__(256) void transpose_f32_bf16(const float* __restrict__ in,
                                                          bfraw* __restrict__ outp,
                                                          int R, int C) {
    __shared__ float tile[32][33];
    int c0 = blockIdx.x * 32, r0 = blockIdx.y * 32;
    int t = threadIdx.x;
    int tr = t >> 3, tc4 = (t & 7) * 4;
    float4 v = *(const float4*)&in[(size_t)(r0 + tr) * C + c0 + tc4];
    tile[tr][tc4 + 0] = v.x; tile[tr][tc4 + 1] = v.y;
    tile[tr][tc4 + 2] = v.z; tile[tr][tc4 + 3] = v.w;
    __syncthreads();
    ushort4 s;
    s.x = f2bf(tile[tc4 + 0][tr]);
    s.y = f2bf(tile[tc4 + 1][tr]);
    s.z = f2bf(tile[tc4 + 2][tr]);
    s.w = f2bf(tile[tc4 + 3][tr]);
    *(ushort4*)&outp[(size_t)(c0 + tr) * R + r0 + tc4] = s;
}

// ------------- merged h+qk GEMM over normb.
// blockIdx.x 0..7  : v cols   -> vT[bg][e][j] (transposed epilogue)
// blockIdx.x 8..15 : gate cols-> gate[row][e] row-major
// blockIdx.x 16    : qk       -> qq/lq/kk row-major + lkT transposed
__global__ __launch_bounds__(256) void gemm_h(const bfraw* __restrict__ A,
                                              const bfraw* __restrict__ WhT,
                                              const bfraw* __restrict__ WqkT,
                                              const float* __restrict__ bias,
                                              const float* __restrict__ bqk,
                                              const float* __restrict__ gamma,
                                              const float* __restrict__ beta,
                                              bfraw* __restrict__ vT,
                                              bfraw* __restrict__ gate,
                                              bfraw* __restrict__ qq,
                                              bfraw* __restrict__ lq,
                                              bfraw* __restrict__ kk,
                                              bfraw* __restrict__ lkT) {
    SMEM_DECL(33280)                       // 4x8KB staging; epi overlays
    bfraw* epi2 = (bfraw*)smem_;
    float* epi = (float*)smem_;
    int t = threadIdx.x;
    int lane = t & 63, wid = t >> 6;
    int wm = wid >> 1, wn = wid & 1;
    int q = lane >> 4, mi = lane & 15;
    int row0 = blockIdx.y * 128, col0 = blockIdx.x * 128;
    bool is_qk = (blockIdx.x == 16);
    f32x4 acc[4][4] = {};
    LDS_DSTS
    {
        const bfraw* Bbase = is_qk ? WqkT : (WhT + (size_t)col0 * DIMD);
        KLOOP_PRE(A + (size_t)row0 * DIMD, DIMD, Bbase, DIMD)
        #pragma unroll
        for (int k0 = 0; k0 < DIMD; k0 += 64) KSTEP64P;
    }
    int bg = row0 >> 8;
    if (is_qk) {
        #pragma unroll
        for (int p = 0; p < 4; ++p) {
            #pragma unroll
            for (int j = 0; j < 4; ++j) {
                float bv = bqk[wn * 64 + j * 16 + mi];
                #pragma unroll
                for (int rg = 0; rg < 4; ++rg)
                    epi[(wm * 16 + q * 4 + rg) * EPIW + wn * 64 + j * 16 + mi] =
                        silu_f(acc[p][j][rg] + bv);
            }
            __syncthreads();
            {
                int lr = t >> 3, c0t = (t & 7) * 16;
                int gr = row0 + epi_row(p, lr);
                const float* src = &epi[lr * EPIW + c0t];
                float z[16];
                #pragma unroll
                for (int k = 0; k < 16; ++k) z[k] = src[k];
                #pragma unroll
                for (int hd = 0; hd < 3; ++hd) {        // 0:qq 1:lq 2:kk
                    bfraw* arr = (hd == 0) ? qq : (hd == 1) ? lq : kk;
                    const float* gp = gamma + hd * QKD + c0t;
                    const float* ep = beta  + hd * QKD + c0t;
                    float tmp[16];
                    #pragma unroll
                    for (int k = 0; k < 16; ++k) tmp[k] = z[k] * gp[k] + ep[k];
                    store16bf(arr + (size_t)gr * QKD + c0t, tmp);
                }
            }
            {
                int c = t >> 1, half = t & 1;
                float g3 = gamma[3 * QKD + c], e3 = beta[3 * QKD + c];
                int j0 = (row0 & 255) + half * 64 + p * 16;
                float tmp[16];
                #pragma unroll
                for (int k = 0; k < 16; ++k)
                    tmp[k] = epi[(half * 16 + k) * EPIW + c] * g3 + e3;
                store16bf(lkT + ((size_t)bg * QKD + c) * GRP + j0, tmp);
            }
            __syncthreads();
        }
        return;
    }
    // h paths: full-tile bf16 epilogue, stride EPB shorts.
    #pragma unroll
    for (int p = 0; p < 4; ++p)
        #pragma unroll
        for (int j = 0; j < 4; ++j) {
            float bv = bias[col0 + wn * 64 + j * 16 + mi];
            #pragma unroll
            for (int rg = 0; rg < 4; ++rg) {
                int rowl = wm * 64 + p * 16 + q * 4 + rg;
                epi2[rowl * EPB + wn * 64 + j * 16 + mi] = f2bf(silu_f(acc[p][j][rg] + bv));
            }
        }
    __syncthreads();
    if (col0 < HIDD) {
        // vT path: thread t -> word-col e2 = t&63 (covers e=2*e2, 2*e2+1), j-block t>>6.
        int e2 = t & 63, jblk = t >> 6;
        const unsigned int* ep32 = (const unsigned int*)epi2;   // EPB/2 = 65 words/row
        unsigned int wv[32];
        #pragma unroll
        for (int jj = 0; jj < 32; ++jj)
            wv[jj] = ep32[(size_t)(jblk * 32 + jj) * 65 + e2];
        int jbase = (row0 & 255) + jblk * 32;
        bfraw* dst0 = vT + ((size_t)bg * HIDD + col0 + 2 * e2) * GRP + jbase;
        bfraw* dst1 = dst0 + GRP;
        #pragma unroll
        for (int vq = 0; vq < 4; ++vq) {
            u16x8 s;
            #pragma unroll
            for (int k = 0; k < 8; ++k) s[k] = (bfraw)(wv[vq * 8 + k] & 0xffffu);
            *(u16x8*)(dst0 + vq * 8) = s;
        }
        #pragma unroll
        for (int vq = 0; vq < 4; ++vq) {
            u16x8 s;
            #pragma unroll
            for (int k = 0; k < 8; ++k) s[k] = (bfraw)(wv[vq * 8 + k] >> 16);
            *(u16x8*)(dst1 + vq * 8) = s;
        }
    } else {
        // gate path: row-major copy-out.
        int lr = t >> 1, seg = t & 1;
        const bfraw* src = epi2 + (size_t)lr * EPB + seg * 64;
        bfraw* dst = gate + (size_t)(row0 + lr) * HIDD + (col0 - HIDD) + seg * 64;
        #pragma unroll
        for (int vq = 0; vq < 8; ++vq)
            *(u16x8*)(dst + vq * 8) = *(const u16x8*)(src + vq * 8);
    }
}

// ------------- sim: attn[bg][i][j] = mask * relu(qq_i . kk_j / G)^2  (bf16 out) -------------
__global__ __launch_bounds__(256) void sim_mfma(const bfraw* __restrict__ qq,
                                                const bfraw* __restrict__ kk,
                                                bfraw* __restrict__ attn) {
    int bg = blockIdx.y;
    int tid = blockIdx.x;
    int ry = (tid == 0) ? 0 : 1;
    int rx = (tid == 2) ? 1 : 0;
    int row0 = ry * 128, col0 = rx * 128;
    SMEM_DECL(32768)
    float* epi = (float*)smem_;
    int t = threadIdx.x;
    int lane = t & 63, wid = t >> 6;
    int wm = wid >> 1, wn = wid & 1;
    int q = lane >> 4, mi = lane & 15;
    f32x4 acc[4][4] = {};
    LDS_DSTS
    {
        KLOOP_PRE(qq + (size_t)(bg * GRP + row0) * QKD, QKD,
                  kk + (size_t)(bg * GRP + col0) * QKD, QKD)
        #pragma unroll
        for (int k0 = 0; k0 < QKD; k0 += 64) KSTEP64P;
    }
    bfraw* ag = attn + (size_t)bg * GRP * GRP;
    #pragma unroll
    for (int p = 0; p < 4; ++p) {
        #pragma unroll
        for (int j = 0; j < 4; ++j) {
            int colg = col0 + wn * 64 + j * 16 + mi;
            #pragma unroll
            for (int rg = 0; rg < 4; ++rg) {
                int rowg = row0 + wm * 64 + p * 16 + q * 4 + rg;
                float s = acc[p][j][rg] * (1.f / GRP);
                s = fmaxf(s, 0.f);
                s = s * s;
                epi[(wm * 16 + q * 4 + rg) * EPIW + wn * 64 + j * 16 + mi] =
                    (colg > rowg) ? 0.f : s;
            }
        }
        __syncthreads();
        int lr = t >> 3, c0t = (t & 7) * 16;
        int gr = row0 + epi_row(p, lr);
        store16bf(ag + (size_t)gr * GRP + col0 + c0t, &epi[lr * EPIW + c0t]);
        __syncthreads();
    }
}

// ------------- kvT_raw[bg][e][d] = sum_j vT[bg][e][j] * lkT[bg][d][j]  (bf16 out) -------------
__global__ __launch_bounds__(256) void kv_mfma(const bfraw* __restrict__ vT,
                                               const bfraw* __restrict__ lkT,
                                               bfraw* __restrict__ kvT_raw) {
    int bg = blockIdx.z;
    int row0 = blockIdx.y * 128;
    SMEM_DECL(32768)
    float* epi = (float*)smem_;
    int t = threadIdx.x;
    int lane = t & 63, wid = t >> 6;
    int wm = wid >> 1, wn = wid & 1;
    int q = lane >> 4, mi = lane & 15;
    f32x4 acc[4][4] = {};
    LDS_DSTS
    {
        KLOOP_PRE(vT + (size_t)bg * HIDD * GRP + (size_t)row0 * GRP, GRP,
                  lkT + (size_t)bg * QKD * GRP, GRP)
        #pragma unroll
        for (int k0 = 0; k0 < GRP; k0 += 64) KSTEP64P;
    }
    bfraw* outg = kvT_raw + (size_t)bg * HIDD * QKD;
    #pragma unroll
    for (int p = 0; p < 4; ++p) {
        #pragma unroll
        for (int j = 0; j < 4; ++j)
            #pragma unroll
            for (int rg = 0; rg < 4; ++rg)
                epi[(wm * 16 + q * 4 + rg) * EPIW + wn * 64 + j * 16 + mi] = acc[p][j][rg];
        __syncthreads();
        int lr = t >> 3, c0t = (t & 7) * 16;
        int gr = row0 + epi_row(p, lr);
        store16bf(outg + (size_t)gr * QKD + c0t, &epi[lr * EPIW + c0t]);
        __syncthreads();
    }
}

// ------------- exclusive cumsum over groups (with /G) -------------
__global__ __launch_bounds__(256) void cumsum2_kernel(const bfraw* __restrict__ raw,
                                                      bfraw* __restrict__ ex) {
    int idx = blockIdx.x * 256 + threadIdx.x;
    int b = idx >> 17;
    int r = idx & 131071;
    const bfraw* rp = raw + (size_t)b * NGRP * 131072 + r;
    bfraw* ep = ex + (size_t)b * NGRP * 131072 + r;
    float run = 0.f;
    #pragma unroll
    for (int g = 0; g < NGRP; ++g) {
        ep[(size_t)g * 131072] = f2bf(run);
        run += bf2f(rp[(size_t)g * 131072]) * (1.f / GRP);
    }
}

// ------------- gated = gate .* (attn@vv + lq@kv_ex)  (bf16 out) -------------
__global__ __launch_bounds__(256) void quadlin_mfma(const bfraw* __restrict__ attn,
                                                    const bfraw* __restrict__ vT,
                                                    const bfraw* __restrict__ lq,
                                                    const bfraw* __restrict__ kvT_ex,
                                                    const bfraw* __restrict__ gate,
                                                    bfraw* __restrict__ gated) {
    int bg = blockIdx.z;
    int row0 = blockIdx.y * 128;
    int col0 = blockIdx.x * 128;
    SMEM_DECL(32768)
    float* epi = (float*)smem_;
    int t = threadIdx.x;
    int lane = t & 63, wid = t >> 6;
    int wm = wid >> 1, wn = wid & 1;
    int q = lane >> 4, mi = lane & 15;
    f32x4 acc[4][4] = {};
    LDS_DSTS
    // Part 1: quadratic. A = attn rows (stride 256), BT = vT rows (stride 256).
    {
        KLOOP_PRE(attn + (size_t)bg * GRP * GRP + (size_t)row0 * GRP, GRP,
                  vT + (size_t)bg * HIDD * GRP + (size_t)col0 * GRP, GRP)
        int kmax = row0 + 128;     // causal: attn[i][j]=0 for j>i
        for (int k0 = 0; k0 < kmax; k0 += 64) KSTEP64P;
    }
    // Part 2: linear. A = lq rows (stride 128), BT = kvT_ex rows (stride 128).
    {
        KLOOP_PRE(lq + (size_t)(bg * GRP + row0) * QKD, QKD,
                  kvT_ex + (size_t)bg * HIDD * QKD + (size_t)col0 * QKD, QKD)
        #pragma unroll
        for (int k0 = 0; k0 < QKD; k0 += 64) KSTEP64P;
    }
    #pragma unroll
    for (int p = 0; p < 4; ++p) {
        #pragma unroll
        for (int j = 0; j < 4; ++j)
            #pragma unroll
            for (int rg = 0; rg < 4; ++rg)
                epi[(wm * 16 + q * 4 + rg) * EPIW + wn * 64 + j * 16 + mi] = acc[p][j][rg];
        __syncthreads();
        int lr = t >> 3, c0t = (t & 7) * 16;
        int gr = row0 + epi_row(p, lr);          // group-local row
        size_t grow = (size_t)bg * GRP + gr;
        const float* src = &epi[lr * EPIW + c0t];
        const bfraw* gsrc = gate + grow * HIDD + col0 + c0t;
        u16x8 g0 = *(const u16x8*)gsrc;
        u16x8 g1 = *(const u16x8*)(gsrc + 8);
        float tmp[16];
        #pragma unroll
        for (int k = 0; k < 8; ++k) tmp[k] = src[k] * bf2f(g0[k]);
        #pragma unroll
        for (int k = 0; k < 8; ++k) tmp[8 + k] = src[8 + k] * bf2f(g1[k]);
        store16bf(gated + grow * HIDD + col0 + c0t, tmp);
        __syncthreads();
    }
}

// ------------- final: out = gated @ WoT^T + bo + x  (fp32 out) -------------
__global__ __launch_bounds__(256) void gemm_final(const bfraw* __restrict__ A,
                                                  const bfraw* __restrict__ BT,
                                                  const float* __restrict__ bo,
                                                  const float* __restrict__ x,
                                                  float* __restrict__ out) {
    SMEM_DECL(32768)
    float* epi = (float*)smem_;
    int t = threadIdx.x;
    int lane = t & 63, wid = t >> 6;
    int wm = wid >> 1, wn = wid & 1;
    int q = lane >> 4, mi = lane & 15;
    int row0 = blockIdx.y * 128, col0 = blockIdx.x * 128;
    f32x4 acc[4][4] = {};
    LDS_DSTS
    {
        KLOOP_PRE(A + (size_t)row0 * HIDD, HIDD, BT + (size_t)col0 * HIDD, HIDD)
        #pragma unroll
        for (int k0 = 0; k0 < HIDD; k0 += 64) KSTEP64P;
    }
    #pragma unroll
    for (int p = 0; p < 4; ++p) {
        #pragma unroll
        for (int j = 0; j < 4; ++j) {
            float bv = bo[col0 + wn * 64 + j * 16 + mi];
            #pragma unroll
            for (int rg = 0; rg < 4; ++rg)
                epi[(wm * 16 + q * 4 + rg) * EPIW + wn * 64 + j * 16 + mi] =
                    acc[p][j][rg] + bv;
        }
        __syncthreads();
        int lr = t >> 3, c0t = (t & 7) * 16;
        int gr = row0 + epi_row(p, lr);
        const float* src = &epi[lr * EPIW + c0t];
        const float* xsrc = x + (size_t)gr * DIMD + col0 + c0t;
        float* dst = out + (size_t)gr * DIMD + col0 + c0t;
        #pragma unroll
        for (int v = 0; v < 4; ++v) {
            float4 a = ((const float4*)src)[v];
            float4 xv = ((const float4*)xsrc)[v];
            a.x += xv.x; a.y += xv.y; a.z += xv.z; a.w += xv.w;
            ((float4*)dst)[v] = a;
        }
        __syncthreads();
    }
}

extern "C" void kernel_launch(void* const* d_in, const int* in_sizes, int n_in,
                              void* d_out, int out_size, void* d_ws, size_t ws_size,
                              hipStream_t stream) {
    const float* x     = (const float*)d_in[0];
    const float* ln_w  = (const float*)d_in[1];
    const float* ln_b  = (const float*)d_in[2];
    const float* Wh    = (const float*)d_in[3];
    const float* bh    = (const float*)d_in[4];
    const float* Wqk   = (const float*)d_in[5];
    const float* bqk   = (const float*)d_in[6];
    const float* gamma = (const float*)d_in[7];
    const float* beta  = (const float*)d_in[8];
    const float* Wo    = (const float*)d_in[9];
    const float* bo    = (const float*)d_in[10];
    float* out = (float*)d_out;

    // d_out (32 MiB) hosts short-lived buffers; all dead before gemm_final writes out.
    char* outb_ = (char*)d_out;
    bfraw* attn = (bfraw*)(outb_);                    //  8 MiB [64][256][256]
    bfraw* qq   = (bfraw*)(outb_ + 8388608);          //  4 MiB [16384][128]
    bfraw* kk   = (bfraw*)(outb_ + 12582912);         //  4 MiB
    bfraw* lq   = (bfraw*)(outb_ + 16777216);         //  4 MiB
    bfraw* WhT  = (bfraw*)(outb_ + 20971520);         //  2 MiB [2048][512]
    bfraw* WqkT = (bfraw*)(outb_ + 23068672);         //  128 KiB [128][512]

    // ws layout (byte offsets):
    char* wsb = (char*)d_ws;
    bfraw* vT      = (bfraw*)(wsb);                   // 32 MiB [64][1024][256]
    bfraw* gate    = (bfraw*)(wsb + 33554432);        // 32 MiB [16384][1024]
    bfraw* gated   = (bfraw*)(wsb + 67108864);        // 32 MiB [16384][1024]
    bfraw* normb   = (bfraw*)(wsb + 100663296);       // 16 MiB [16384][512]
    bfraw* kvT_raw = (bfraw*)(wsb + 117440512);       // 16 MiB [64][1024][128]
    bfraw* kvT_ex  = (bfraw*)(wsb + 134217728);       // 16 MiB [64][1024][128]
    bfraw* lkT     = (bfraw*)(wsb + 150994944);       //  4 MiB [64][128][256]
    bfraw* WoT     = (bfraw*)(wsb + 155189248);       //  1 MiB [512][1024]

    // 0-2. weight transposes to bf16 [N][K]
    transpose_f32_bf16<<<dim3(2 * HIDD / 32, DIMD / 32), 256, 0, stream>>>(Wh, WhT, DIMD, 2 * HIDD);
    transpose_f32_bf16<<<dim3(DIMD / 32, HIDD / 32), 256, 0, stream>>>(Wo, WoT, HIDD, DIMD);
    transpose_f32_bf16<<<dim3(QKD / 32, DIMD / 32), 256, 0, stream>>>(Wqk, WqkT, DIMD, QKD);
    // 3. LayerNorm -> normb bf16
    ln_kernel<<<TROWS / 4, 256, 0, stream>>>(x, ln_w, ln_b, normb);
    // 4. merged h+qk GEMM: vT + gate + qq/lq/kk/lkT  (17 column tiles)
    gemm_h<<<dim3(17, TROWS / 128), 256, 0, stream>>>(
        normb, WhT, WqkT, bh, bqk, gamma, beta, vT, gate, qq, lq, kk, lkT);
    // 5. attn = mask(relu(qq @ kk^T / G)^2)
    sim_mfma<<<dim3(3, BGRP), 256, 0, stream>>>(qq, kk, attn);
    // 6. kvT_raw[e][d] = sum_j vT[e][j]*lkT[d][j]
    kv_mfma<<<dim3(1, HIDD / 128, BGRP), 256, 0, stream>>>(vT, lkT, kvT_raw);
    // 7. exclusive cumsum over groups (with /G) -> kvT_ex
    cumsum2_kernel<<<(BATCH * QKD * HIDD) / 256, 256, 0, stream>>>(kvT_raw, kvT_ex);
    // 8. gated = gate .* (attn@vv + lq@kv_ex)
    quadlin_mfma<<<dim3(HIDD / 128, GRP / 128, BGRP), 256, 0, stream>>>(
        attn, vT, lq, kvT_ex, gate, gated);
    // 9. out = gated @ Wo + bo + x
    gemm_final<<<dim3(DIMD / 128, TROWS / 128), 256, 0, stream>>>(gated, WoT, bo, x, out);
}

// Round 10
// 282.613 us; speedup vs baseline: 1.0845x; 1.0437x over previous
//
#include <hip/hip_runtime.h>
#include <hip/hip_bf16.h>
#include <math.h>

// FLASH (GAU-style) fused block. Round 9: dispatch consolidation —
// ln+transposes fused (prep_kernel), sim+kv fused (simkv_kernel).
// K-loop structure unchanged from R8 (merged h+qk GEMM, 128x128 tiles).
// b=4, n=4096, dim=512, hid=1024, qk=128, group=256.

#define BATCH 4
#define SEQ   4096
#define TROWS 16384      // BATCH*SEQ
#define DIMD  512
#define HIDD  1024
#define QKD   128
#define GRP   256
#define NGRP  16         // SEQ/GRP
#define BGRP  64         // BATCH*NGRP
#define EPIW  132        // padded LDS epilogue row stride (f32 path)
#define EPB   130        // bf16 full-tile epilogue row stride (shorts)

typedef unsigned short bfraw;
typedef __attribute__((ext_vector_type(8))) short bf16x8;
typedef __attribute__((ext_vector_type(8))) unsigned short u16x8;
typedef __attribute__((ext_vector_type(4))) unsigned int u32x4;
typedef __attribute__((ext_vector_type(4))) float f32x4;

__device__ __forceinline__ float bf2f(bfraw u) {
    union { float f; unsigned int i; } c;
    c.i = ((unsigned int)u) << 16;
    return c.f;
}
__device__ __forceinline__ bfraw f2bf(float f) {
    unsigned int x = __float_as_uint(f);
    unsigned int r = (x + 0x7fffu + ((x >> 16) & 1u)) >> 16;   // RNE
    return (bfraw)r;
}
__device__ __forceinline__ unsigned int pkbf(float lo, float hi) {
    __hip_bfloat162 h2 = __float22bfloat162_rn(make_float2(lo, hi));
    union { __hip_bfloat162 h; unsigned int u; } c; c.h = h2;
    return c.u;
}
// 16 contiguous f32 -> 16 bf16 at dst (two 16B stores), packed cvt.
__device__ __forceinline__ void store16bf(bfraw* dst, const float* src) {
    u32x4 a, b;
    #pragma unroll
    for (int k = 0; k < 4; ++k) a[k] = pkbf(src[2 * k], src[2 * k + 1]);
    #pragma unroll
    for (int k = 0; k < 4; ++k) b[k] = pkbf(src[8 + 2 * k], src[8 + 2 * k + 1]);
    *(u32x4*)dst = a;
    *(u32x4*)(dst + 8) = b;
}
__device__ __forceinline__ float silu_f(float z) {
    return z / (1.f + __expf(-z));
}
__device__ __forceinline__ void gload_lds16(const void* g, void* l) {
    __builtin_amdgcn_global_load_lds(
        (const __attribute__((address_space(1))) unsigned int*)g,
        (__attribute__((address_space(3))) unsigned int*)l, 16, 0, 0);
}

// One BK=32 MFMA step on staged tiles (4 waves, each 64x64 = 4x4 frags).
__device__ __forceinline__ void mfma_step(const bfraw* As, const bfraw* Bs,
                                          f32x4 acc[4][4], int wm, int wn,
                                          int q, int mi) {
    bf16x8 af[4], bfg[4];
    #pragma unroll
    for (int i = 0; i < 4; ++i)
        af[i] = *(const bf16x8*)&As[(size_t)(wm * 64 + i * 16 + mi) * 32 + q * 8];
    #pragma unroll
    for (int j = 0; j < 4; ++j)
        bfg[j] = *(const bf16x8*)&Bs[(size_t)(wn * 64 + j * 16 + mi) * 32 + q * 8];
    #pragma unroll
    for (int i = 0; i < 4; ++i)
        #pragma unroll
        for (int j = 0; j < 4; ++j)
            acc[i][j] = __builtin_amdgcn_mfma_f32_16x16x32_bf16(af[i], bfg[j], acc[i][j], 0, 0, 0);
}

#define SMEM_DECL(sz)                                           \
    __shared__ __align__(16) char smem_[sz];                    \
    bfraw* As0 = (bfraw*)smem_;                                 \
    bfraw* As1 = (bfraw*)(smem_ + 8192);                        \
    bfraw* Bs0 = (bfraw*)(smem_ + 16384);                       \
    bfraw* Bs1 = (bfraw*)(smem_ + 24576);

#define KLOOP_PRE(Abase, Astr, Bbase, Bstr)                                    \
    const bfraw* pa0 = (Abase) + (size_t)(t >> 2) * (Astr) + (t & 3) * 8;      \
    const bfraw* pa1 = pa0 + (size_t)64 * (Astr);                              \
    const bfraw* pb0 = (Bbase) + (size_t)(t >> 2) * (Bstr) + (t & 3) * 8;      \
    const bfraw* pb1 = pb0 + (size_t)64 * (Bstr);

#define LDS_DSTS                                                               \
    bfraw* lA0  = As0 + (size_t)wid * 512;                                     \
    bfraw* lA0b = As0 + 2048 + (size_t)wid * 512;                              \
    bfraw* lA1  = As1 + (size_t)wid * 512;                                     \
    bfraw* lA1b = As1 + 2048 + (size_t)wid * 512;                              \
    bfraw* lB0  = Bs0 + (size_t)wid * 512;                                     \
    bfraw* lB0b = Bs0 + 2048 + (size_t)wid * 512;                              \
    bfraw* lB1  = Bs1 + (size_t)wid * 512;                                     \
    bfraw* lB1b = Bs1 + 2048 + (size_t)wid * 512;

#define KSTEP64P                                                               \
    do {                                                                       \
        gload_lds16(pa0,      lA0);                                            \
        gload_lds16(pa1,      lA0b);                                           \
        gload_lds16(pa0 + 32, lA1);                                            \
        gload_lds16(pa1 + 32, lA1b);                                           \
        gload_lds16(pb0,      lB0);                                            \
        gload_lds16(pb1,      lB0b);                                           \
        gload_lds16(pb0 + 32, lB1);                                            \
        gload_lds16(pb1 + 32, lB1b);                                           \
        __syncthreads();                                                       \
        mfma_step(As0, Bs0, acc, wm, wn, q, mi);                               \
        mfma_step(As1, Bs1, acc, wm, wn, q, mi);                               \
        __syncthreads();                                                       \
        pa0 += 64; pa1 += 64; pb0 += 64; pb1 += 64;                            \
    } while (0)

__device__ __forceinline__ int epi_row(int p, int lr) {
    return (lr < 16) ? (p * 16 + lr) : (64 + p * 16 + (lr - 16));
}

// ------------- prep: ln (blocks 0..4095) + 3 weight transposes -------------
// blocks 4096..5119: Wh [512x2048]; 5120..5631: Wo [1024x512]; 5632..5695: Wqk [512x128].
__global__ __launch_bounds__(256) void prep_kernel(const float* __restrict__ x,
                                                   const float* __restrict__ lnw,
                                                   const float* __restrict__ lnb,
                                                   const float* __restrict__ Wh,
                                                   const float* __restrict__ Wo,
                                                   const float* __restrict__ Wqk,
                                                   bfraw* __restrict__ normb,
                                                   bfraw* __restrict__ WhT,
                                                   bfraw* __restrict__ WoT,
                                                   bfraw* __restrict__ WqkT) {
    __shared__ float tile[32][33];
    int bid = blockIdx.x;
    int t = threadIdx.x;
    if (bid < 4096) {
        // LayerNorm: one wave per row of 512
        int row  = bid * 4 + (t >> 6);
        int lane = t & 63;
        const float* xr = x + (size_t)row * DIMD;
        float4 v0 = ((const float4*)xr)[lane];
        float4 v1 = ((const float4*)xr)[lane + 64];
        float s  = v0.x + v0.y + v0.z + v0.w + v1.x + v1.y + v1.z + v1.w;
        float ss = v0.x*v0.x + v0.y*v0.y + v0.z*v0.z + v0.w*v0.w
                 + v1.x*v1.x + v1.y*v1.y + v1.z*v1.z + v1.w*v1.w;
        #pragma unroll
        for (int off = 32; off; off >>= 1) {
            s  += __shfl_xor(s, off);
            ss += __shfl_xor(ss, off);
        }
        float mu  = s * (1.f / DIMD);
        float var = ss * (1.f / DIMD) - mu * mu;
        float inv = rsqrtf(var + 1e-5f);
        float4 w0 = ((const float4*)lnw)[lane],  w1 = ((const float4*)lnw)[lane + 64];
        float4 b0 = ((const float4*)lnb)[lane],  b1 = ((const float4*)lnb)[lane + 64];
        unsigned int o0 = pkbf((v0.x - mu) * inv * w0.x + b0.x,
                               (v0.y - mu) * inv * w0.y + b0.y);
        unsigned int o1 = pkbf((v0.z - mu) * inv * w0.z + b0.z,
                               (v0.w - mu) * inv * w0.w + b0.w);
        unsigned int o2 = pkbf((v1.x - mu) * inv * w1.x + b1.x,
                               (v1.y - mu) * inv * w1.y + b1.y);
        unsigned int o3 = pkbf((v1.z - mu) * inv * w1.z + b1.z,
                               (v1.w - mu) * inv * w1.w + b1.w);
        unsigned int* brow = (unsigned int*)(normb + (size_t)row * DIMD);
        ((uint2*)brow)[lane]      = make_uint2(o0, o1);
        ((uint2*)brow)[lane + 64] = make_uint2(o2, o3);
        return;
    }
    bid -= 4096;
    const float* in; bfraw* outp; int R, C, nx;
    if (bid < 1024)      { in = Wh;  outp = WhT;  R = DIMD; C = 2 * HIDD; nx = 64; }
    else if (bid < 1536) { bid -= 1024; in = Wo;  outp = WoT;  R = HIDD; C = DIMD; nx = 16; }
    else                 { bid -= 1536; in = Wqk; outp = WqkT; R = DIMD; C = QKD;  nx = 4; }
    int c0 = (bid % nx) * 32, r0 = (bid / nx) * 32;
    int tr = t >> 3, tc4 = (t & 7) * 4;
    float4 v = *(const float4*)&in[(size_t)(r0 + tr) * C + c0 + tc4];
    tile[tr][tc4 + 0] = v.x; tile[tr][tc4 + 1] = v.y;
    tile[tr][tc4 + 2] = v.z; tile[tr][tc4 + 3] = v.w;
    __syncthreads();
    ushort4 s;
    s.x = f2bf(tile[tc4 + 0][tr]);
    s.y = f2bf(tile[tc4 + 1][tr]);
    s.z = f2bf(tile[tc4 + 2][tr]);
    s.w = f2bf(tile[tc4 + 3][tr]);
    *(ushort4*)&outp[(size_t)(c0 + tr) * R + r0 + tc4] = s;
}

// ------------- merged h+qk GEMM over normb (unchanged from R8) -------------
// blockIdx.x 0..7  : v cols   -> vT[bg][e][j] (transposed epilogue)
// blockIdx.x 8..15 : gate cols-> gate[row][e] row-major
// blockIdx.x 16    : qk       -> qq/lq/kk row-major + lkT transposed
__global__ __launch_bounds__(256) void gemm_h(const bfraw* __restrict__ A,
                                              const bfraw* __restrict__ WhT,
                                              const bfraw* __restrict__ WqkT,
                                              const float* __restrict__ bias,
                                              const float* __restrict__ bqk,
                                              const float* __restrict__ gamma,
                                              const float* __restrict__ beta,
                                              bfraw* __restrict__ vT,
                                              bfraw* __restrict__ gate,
                                              bfraw* __restrict__ qq,
                                              bfraw* __restrict__ lq,
                                              bfraw* __restrict__ kk,
                                              bfraw* __restrict__ lkT) {
    SMEM_DECL(33280)                       // 4x8KB staging; epi overlays
    bfraw* epi2 = (bfraw*)smem_;
    float* epi = (float*)smem_;
    int t = threadIdx.x;
    int lane = t & 63, wid = t >> 6;
    int wm = wid >> 1, wn = wid & 1;
    int q = lane >> 4, mi = lane & 15;
    int row0 = blockIdx.y * 128, col0 = blockIdx.x * 128;
    bool is_qk = (blockIdx.x == 16);
    f32x4 acc[4][4] = {};
    LDS_DSTS
    {
        const bfraw* Bbase = is_qk ? WqkT : (WhT + (size_t)col0 * DIMD);
        KLOOP_PRE(A + (size_t)row0 * DIMD, DIMD, Bbase, DIMD)
        #pragma unroll
        for (int k0 = 0; k0 < DIMD; k0 += 64) KSTEP64P;
    }
    int bg = row0 >> 8;
    if (is_qk) {
        #pragma unroll
        for (int p = 0; p < 4; ++p) {
            #pragma unroll
            for (int j = 0; j < 4; ++j) {
                float bv = bqk[wn * 64 + j * 16 + mi];
                #pragma unroll
                for (int rg = 0; rg < 4; ++rg)
                    epi[(wm * 16 + q * 4 + rg) * EPIW + wn * 64 + j * 16 + mi] =
                        silu_f(acc[p][j][rg] + bv);
            }
            __syncthreads();
            {
                int lr = t >> 3, c0t = (t & 7) * 16;
                int gr = row0 + epi_row(p, lr);
                const float* src = &epi[lr * EPIW + c0t];
                float z[16];
                #pragma unroll
                for (int k = 0; k < 16; ++k) z[k] = src[k];
                #pragma unroll
                for (int hd = 0; hd < 3; ++hd) {        // 0:qq 1:lq 2:kk
                    bfraw* arr = (hd == 0) ? qq : (hd == 1) ? lq : kk;
                    const float* gp = gamma + hd * QKD + c0t;
                    const float* ep = beta  + hd * QKD + c0t;
                    float tmp[16];
                    #pragma unroll
                    for (int k = 0; k < 16; ++k) tmp[k] = z[k] * gp[k] + ep[k];
                    store16bf(arr + (size_t)gr * QKD + c0t, tmp);
                }
            }
            {
                int c = t >> 1, half = t & 1;
                float g3 = gamma[3 * QKD + c], e3 = beta[3 * QKD + c];
                int j0 = (row0 & 255) + half * 64 + p * 16;
                float tmp[16];
                #pragma unroll
                for (int k = 0; k < 16; ++k)
                    tmp[k] = epi[(half * 16 + k) * EPIW + c] * g3 + e3;
                store16bf(lkT + ((size_t)bg * QKD + c) * GRP + j0, tmp);
            }
            __syncthreads();
        }
        return;
    }
    // h paths: full-tile bf16 epilogue, stride EPB shorts.
    #pragma unroll
    for (int p = 0; p < 4; ++p)
        #pragma unroll
        for (int j = 0; j < 4; ++j) {
            float bv = bias[col0 + wn * 64 + j * 16 + mi];
            #pragma unroll
            for (int rg = 0; rg < 4; ++rg) {
                int rowl = wm * 64 + p * 16 + q * 4 + rg;
                epi2[rowl * EPB + wn * 64 + j * 16 + mi] = f2bf(silu_f(acc[p][j][rg] + bv));
            }
        }
    __syncthreads();
    if (col0 < HIDD) {
        // vT path: thread t -> word-col e2 = t&63 (covers e=2*e2, 2*e2+1), j-block t>>6.
        int e2 = t & 63, jblk = t >> 6;
        const unsigned int* ep32 = (const unsigned int*)epi2;   // EPB/2 = 65 words/row
        unsigned int wv[32];
        #pragma unroll
        for (int jj = 0; jj < 32; ++jj)
            wv[jj] = ep32[(size_t)(jblk * 32 + jj) * 65 + e2];
        int jbase = (row0 & 255) + jblk * 32;
        bfraw* dst0 = vT + ((size_t)bg * HIDD + col0 + 2 * e2) * GRP + jbase;
        bfraw* dst1 = dst0 + GRP;
        #pragma unroll
        for (int vq = 0; vq < 4; ++vq) {
            u16x8 s;
            #pragma unroll
            for (int k = 0; k < 8; ++k) s[k] = (bfraw)(wv[vq * 8 + k] & 0xffffu);
            *(u16x8*)(dst0 + vq * 8) = s;
        }
        #pragma unroll
        for (int vq = 0; vq < 4; ++vq) {
            u16x8 s;
            #pragma unroll
            for (int k = 0; k < 8; ++k) s[k] = (bfraw)(wv[vq * 8 + k] >> 16);
            *(u16x8*)(dst1 + vq * 8) = s;
        }
    } else {
        // gate path: row-major copy-out.
        int lr = t >> 1, seg = t & 1;
        const bfraw* src = epi2 + (size_t)lr * EPB + seg * 64;
        bfraw* dst = gate + (size_t)(row0 + lr) * HIDD + (col0 - HIDD) + seg * 64;
        #pragma unroll
        for (int vq = 0; vq < 8; ++vq)
            *(u16x8*)(dst + vq * 8) = *(const u16x8*)(src + vq * 8);
    }
}

// ------------- fused sim + kv dispatch.
// blocks 0..511: kv (bg = bid>>3, row0 = (bid&7)*128)
// blocks 512..703: sim (i = bid-512; bg = i%64, tile = i/64)
__global__ __launch_bounds__(256) void simkv_kernel(const bfraw* __restrict__ qq,
                                                    const bfraw* __restrict__ kk,
                                                    bfraw* __restrict__ attn,
                                                    const bfraw* __restrict__ vT,
                                                    const bfraw* __restrict__ lkT,
                                                    bfraw* __restrict__ kvT_raw) {
    SMEM_DECL(32768)
    float* epi = (float*)smem_;
    int t = threadIdx.x;
    int lane = t & 63, wid = t >> 6;
    int wm = wid >> 1, wn = wid & 1;
    int q = lane >> 4, mi = lane & 15;
    int bid = blockIdx.x;
    f32x4 acc[4][4] = {};
    LDS_DSTS
    if (bid < 512) {
        // ---- kv: kvT_raw[bg][e][d] = sum_j vT[bg][e][j] * lkT[bg][d][j] ----
        int bg = bid >> 3;
        int row0 = (bid & 7) * 128;
        {
            KLOOP_PRE(vT + (size_t)bg * HIDD * GRP + (size_t)row0 * GRP, GRP,
                      lkT + (size_t)bg * QKD * GRP, GRP)
            #pragma unroll
            for (int k0 = 0; k0 < GRP; k0 += 64) KSTEP64P;
        }
        bfraw* outg = kvT_raw + (size_t)bg * HIDD * QKD;
        #pragma unroll
        for (int p = 0; p < 4; ++p) {
            #pragma unroll
            for (int j = 0; j < 4; ++j)
                #pragma unroll
                for (int rg = 0; rg < 4; ++rg)
                    epi[(wm * 16 + q * 4 + rg) * EPIW + wn * 64 + j * 16 + mi] = acc[p][j][rg];
            __syncthreads();
            int lr = t >> 3, c0t = (t & 7) * 16;
            int gr = row0 + epi_row(p, lr);
            store16bf(outg + (size_t)gr * QKD + c0t, &epi[lr * EPIW + c0t]);
            __syncthreads();
        }
        return;
    }
    // ---- sim: attn[bg][i][j] = mask * relu(qq_i . kk_j / G)^2 ----
    int i = bid - 512;
    int bg = i & 63;
    int tid = i >> 6;
    int ry = (tid == 0) ? 0 : 1;
    int rx = (tid == 2) ? 1 : 0;
    int row0 = ry * 128, col0 = rx * 128;
    {
        KLOOP_PRE(qq + (size_t)(bg * GRP + row0) * QKD, QKD,
                  kk + (size_t)(bg * GRP + col0) * QKD, QKD)
        #pragma unroll
        for (int k0 = 0; k0 < QKD; k0 += 64) KSTEP64P;
    }
    bfraw* ag = attn + (size_t)bg * GRP * GRP;
    #pragma unroll
    for (int p = 0; p < 4; ++p) {
        #pragma unroll
        for (int j = 0; j < 4; ++j) {
            int colg = col0 + wn * 64 + j * 16 + mi;
            #pragma unroll
            for (int rg = 0; rg < 4; ++rg) {
                int rowg = row0 + wm * 64 + p * 16 + q * 4 + rg;
                float s = acc[p][j][rg] * (1.f / GRP);
                s = fmaxf(s, 0.f);
                s = s * s;
                epi[(wm * 16 + q * 4 + rg) * EPIW + wn * 64 + j * 16 + mi] =
                    (colg > rowg) ? 0.f : s;
            }
        }
        __syncthreads();
        int lr = t >> 3, c0t = (t & 7) * 16;
        int gr = row0 + epi_row(p, lr);
        store16bf(ag + (size_t)gr * GRP + col0 + c0t, &epi[lr * EPIW + c0t]);
        __syncthreads();
    }
}

// ------------- exclusive cumsum over groups (with /G) -------------
__global__ __launch_bounds__(256) void cumsum2_kernel(const bfraw* __restrict__ raw,
                                                      bfraw* __restrict__ ex) {
    int idx = blockIdx.x * 256 + threadIdx.x;
    int b = idx >> 17;
    int r = idx & 131071;
    const bfraw* rp = raw + (size_t)b * NGRP * 131072 + r;
    bfraw* ep = ex + (size_t)b * NGRP * 131072 + r;
    float run = 0.f;
    #pragma unroll
    for (int g = 0; g < NGRP; ++g) {
        ep[(size_t)g * 131072] = f2bf(run);
        run += bf2f(rp[(size_t)g * 131072]) * (1.f / GRP);
    }
}

// ------------- gated = gate .* (attn@vv + lq@kv_ex)  (bf16 out) -------------
__global__ __launch_bounds__(256) void quadlin_mfma(const bfraw* __restrict__ attn,
                                                    const bfraw* __restrict__ vT,
                                                    const bfraw* __restrict__ lq,
                                                    const bfraw* __restrict__ kvT_ex,
                                                    const bfraw* __restrict__ gate,
                                                    bfraw* __restrict__ gated) {
    int bg = blockIdx.z;
    int row0 = blockIdx.y * 128;
    int col0 = blockIdx.x * 128;
    SMEM_DECL(32768)
    float* epi = (float*)smem_;
    int t = threadIdx.x;
    int lane = t & 63, wid = t >> 6;
    int wm = wid >> 1, wn = wid & 1;
    int q = lane >> 4, mi = lane & 15;
    f32x4 acc[4][4] = {};
    LDS_DSTS
    // Part 1: quadratic. A = attn rows (stride 256), BT = vT rows (stride 256).
    {
        KLOOP_PRE(attn + (size_t)bg * GRP * GRP + (size_t)row0 * GRP, GRP,
                  vT + (size_t)bg * HIDD * GRP + (size_t)col0 * GRP, GRP)
        int kmax = row0 + 128;     // causal: attn[i][j]=0 for j>i
        for (int k0 = 0; k0 < kmax; k0 += 64) KSTEP64P;
    }
    // Part 2: linear. A = lq rows (stride 128), BT = kvT_ex rows (stride 128).
    {
        KLOOP_PRE(lq + (size_t)(bg * GRP + row0) * QKD, QKD,
                  kvT_ex + (size_t)bg * HIDD * QKD + (size_t)col0 * QKD, QKD)
        #pragma unroll
        for (int k0 = 0; k0 < QKD; k0 += 64) KSTEP64P;
    }
    #pragma unroll
    for (int p = 0; p < 4; ++p) {
        #pragma unroll
        for (int j = 0; j < 4; ++j)
            #pragma unroll
            for (int rg = 0; rg < 4; ++rg)
                epi[(wm * 16 + q * 4 + rg) * EPIW + wn * 64 + j * 16 + mi] = acc[p][j][rg];
        __syncthreads();
        int lr = t >> 3, c0t = (t & 7) * 16;
        int gr = row0 + epi_row(p, lr);          // group-local row
        size_t grow = (size_t)bg * GRP + gr;
        const float* src = &epi[lr * EPIW + c0t];
        const bfraw* gsrc = gate + grow * HIDD + col0 + c0t;
        u16x8 g0 = *(const u16x8*)gsrc;
        u16x8 g1 = *(const u16x8*)(gsrc + 8);
        float tmp[16];
        #pragma unroll
        for (int k = 0; k < 8; ++k) tmp[k] = src[k] * bf2f(g0[k]);
        #pragma unroll
        for (int k = 0; k < 8; ++k) tmp[8 + k] = src[8 + k] * bf2f(g1[k]);
        store16bf(gated + grow * HIDD + col0 + c0t, tmp);
        __syncthreads();
    }
}

// ------------- final: out = gated @ WoT^T + bo + x  (fp32 out) -------------
__global__ __launch_bounds__(256) void gemm_final(const bfraw* __restrict__ A,
                                                  const bfraw* __restrict__ BT,
                                                  const float* __restrict__ bo,
                                                  const float* __restrict__ x,
                                                  float* __restrict__ out) {
    SMEM_DECL(32768)
    float* epi = (float*)smem_;
    int t = threadIdx.x;
    int lane = t & 63, wid = t >> 6;
    int wm = wid >> 1, wn = wid & 1;
    int q = lane >> 4, mi = lane & 15;
    int row0 = blockIdx.y * 128, col0 = blockIdx.x * 128;
    f32x4 acc[4][4] = {};
    LDS_DSTS
    {
        KLOOP_PRE(A + (size_t)row0 * HIDD, HIDD, BT + (size_t)col0 * HIDD, HIDD)
        #pragma unroll
        for (int k0 = 0; k0 < HIDD; k0 += 64) KSTEP64P;
    }
    #pragma unroll
    for (int p = 0; p < 4; ++p) {
        #pragma unroll
        for (int j = 0; j < 4; ++j) {
            float bv = bo[col0 + wn * 64 + j * 16 + mi];
            #pragma unroll
            for (int rg = 0; rg < 4; ++rg)
                epi[(wm * 16 + q * 4 + rg) * EPIW + wn * 64 + j * 16 + mi] =
                    acc[p][j][rg] + bv;
        }
        __syncthreads();
        int lr = t >> 3, c0t = (t & 7) * 16;
        int gr = row0 + epi_row(p, lr);
        const float* src = &epi[lr * EPIW + c0t];
        const float* xsrc = x + (size_t)gr * DIMD + col0 + c0t;
        float* dst = out + (size_t)gr * DIMD + col0 + c0t;
        #pragma unroll
        for (int v = 0; v < 4; ++v) {
            float4 a = ((const float4*)src)[v];
            float4 xv = ((const float4*)xsrc)[v];
            a.x += xv.x; a.y += xv.y; a.z += xv.z; a.w += xv.w;
            ((float4*)dst)[v] = a;
        }
        __syncthreads();
    }
}

extern "C" void kernel_launch(void* const* d_in, const int* in_sizes, int n_in,
                              void* d_out, int out_size, void* d_ws, size_t ws_size,
                              hipStream_t stream) {
    const float* x     = (const float*)d_in[0];
    const float* ln_w  = (const float*)d_in[1];
    const float* ln_b  = (const float*)d_in[2];
    const float* Wh    = (const float*)d_in[3];
    const float* bh    = (const float*)d_in[4];
    const float* Wqk   = (const float*)d_in[5];
    const float* bqk   = (const float*)d_in[6];
    const float* gamma = (const float*)d_in[7];
    const float* beta  = (const float*)d_in[8];
    const float* Wo    = (const float*)d_in[9];
    const float* bo    = (const float*)d_in[10];
    float* out = (float*)d_out;

    // d_out (32 MiB) hosts short-lived buffers; all dead before gemm_final writes out.
    char* outb_ = (char*)d_out;
    bfraw* attn = (bfraw*)(outb_);                    //  8 MiB [64][256][256]
    bfraw* qq   = (bfraw*)(outb_ + 8388608);          //  4 MiB [16384][128]
    bfraw* kk   = (bfraw*)(outb_ + 12582912);         //  4 MiB
    bfraw* lq   = (bfraw*)(outb_ + 16777216);         //  4 MiB
    bfraw* WhT  = (bfraw*)(outb_ + 20971520);         //  2 MiB [2048][512]
    bfraw* WqkT = (bfraw*)(outb_ + 23068672);         //  128 KiB [128][512]

    // ws layout (byte offsets):
    char* wsb = (char*)d_ws;
    bfraw* vT      = (bfraw*)(wsb);                   // 32 MiB [64][1024][256]
    bfraw* gate    = (bfraw*)(wsb + 33554432);        // 32 MiB [16384][1024]
    bfraw* gated   = (bfraw*)(wsb + 67108864);        // 32 MiB [16384][1024]
    bfraw* normb   = (bfraw*)(wsb + 100663296);       // 16 MiB [16384][512]
    bfraw* kvT_raw = (bfraw*)(wsb + 117440512);       // 16 MiB [64][1024][128]
    bfraw* kvT_ex  = (bfraw*)(wsb + 134217728);       // 16 MiB [64][1024][128]
    bfraw* lkT     = (bfraw*)(wsb + 150994944);       //  4 MiB [64][128][256]
    bfraw* WoT     = (bfraw*)(wsb + 155189248);       //  1 MiB [512][1024]

    // 1. prep: LayerNorm + all weight transposes (one dispatch)
    prep_kernel<<<4096 + 1024 + 512 + 64, 256, 0, stream>>>(
        x, ln_w, ln_b, Wh, Wo, Wqk, normb, WhT, WoT, WqkT);
    // 2. merged h+qk GEMM: vT + gate + qq/lq/kk/lkT  (17 column tiles)
    gemm_h<<<dim3(17, TROWS / 128), 256, 0, stream>>>(
        normb, WhT, WqkT, bh, bqk, gamma, beta, vT, gate, qq, lq, kk, lkT);
    // 3. fused kv + sim (one dispatch; kv blocks first)
    simkv_kernel<<<512 + 192, 256, 0, stream>>>(qq, kk, attn, vT, lkT, kvT_raw);
    // 4. exclusive cumsum over groups (with /G) -> kvT_ex
    cumsum2_kernel<<<(BATCH * QKD * HIDD) / 256, 256, 0, stream>>>(kvT_raw, kvT_ex);
    // 5. gated = gate .* (attn@vv + lq@kv_ex)
    quadlin_mfma<<<dim3(HIDD / 128, GRP / 128, BGRP), 256, 0, stream>>>(
        attn, vT, lq, kvT_ex, gate, gated);
    // 6. out = gated @ Wo + bo + x
    gemm_final<<<dim3(DIMD / 128, TROWS / 128), 256, 0, stream>>>(gated, WoT, bo, x, out);
}

// Round 11
// 282.611 us; speedup vs baseline: 1.0845x; 1.0000x over previous
//
#include <hip/hip_runtime.h>
#include <hip/hip_bf16.h>
#include <math.h>

// FLASH (GAU-style) fused block. Round 10: software-pipelined double-buffered
// K-loop (prefetch k+1 while computing k; one barrier per BK=32 whose vmcnt
// drain lands AFTER a full MFMA step). Dispatch structure unchanged from R9.
// b=4, n=4096, dim=512, hid=1024, qk=128, group=256.

#define BATCH 4
#define SEQ   4096
#define TROWS 16384      // BATCH*SEQ
#define DIMD  512
#define HIDD  1024
#define QKD   128
#define GRP   256
#define NGRP  16         // SEQ/GRP
#define BGRP  64         // BATCH*NGRP
#define EPIW  132        // padded LDS epilogue row stride (f32 path)
#define EPB   130        // bf16 full-tile epilogue row stride (shorts)

typedef unsigned short bfraw;
typedef __attribute__((ext_vector_type(8))) short bf16x8;
typedef __attribute__((ext_vector_type(8))) unsigned short u16x8;
typedef __attribute__((ext_vector_type(4))) unsigned int u32x4;
typedef __attribute__((ext_vector_type(4))) float f32x4;

__device__ __forceinline__ float bf2f(bfraw u) {
    union { float f; unsigned int i; } c;
    c.i = ((unsigned int)u) << 16;
    return c.f;
}
__device__ __forceinline__ bfraw f2bf(float f) {
    unsigned int x = __float_as_uint(f);
    unsigned int r = (x + 0x7fffu + ((x >> 16) & 1u)) >> 16;   // RNE
    return (bfraw)r;
}
__device__ __forceinline__ unsigned int pkbf(float lo, float hi) {
    __hip_bfloat162 h2 = __float22bfloat162_rn(make_float2(lo, hi));
    union { __hip_bfloat162 h; unsigned int u; } c; c.h = h2;
    return c.u;
}
// 16 contiguous f32 -> 16 bf16 at dst (two 16B stores), packed cvt.
__device__ __forceinline__ void store16bf(bfraw* dst, const float* src) {
    u32x4 a, b;
    #pragma unroll
    for (int k = 0; k < 4; ++k) a[k] = pkbf(src[2 * k], src[2 * k + 1]);
    #pragma unroll
    for (int k = 0; k < 4; ++k) b[k] = pkbf(src[8 + 2 * k], src[8 + 2 * k + 1]);
    *(u32x4*)dst = a;
    *(u32x4*)(dst + 8) = b;
}
__device__ __forceinline__ float silu_f(float z) {
    return z / (1.f + __expf(-z));
}
__device__ __forceinline__ void gload_lds16(const void* g, void* l) {
    __builtin_amdgcn_global_load_lds(
        (const __attribute__((address_space(1))) unsigned int*)g,
        (__attribute__((address_space(3))) unsigned int*)l, 16, 0, 0);
}

// One BK=32 MFMA step on staged tiles (4 waves, each 64x64 = 4x4 frags).
__device__ __forceinline__ void mfma_step(const bfraw* As, const bfraw* Bs,
                                          f32x4 acc[4][4], int wm, int wn,
                                          int q, int mi) {
    bf16x8 af[4], bfg[4];
    #pragma unroll
    for (int i = 0; i < 4; ++i)
        af[i] = *(const bf16x8*)&As[(size_t)(wm * 64 + i * 16 + mi) * 32 + q * 8];
    #pragma unroll
    for (int j = 0; j < 4; ++j)
        bfg[j] = *(const bf16x8*)&Bs[(size_t)(wn * 64 + j * 16 + mi) * 32 + q * 8];
    #pragma unroll
    for (int i = 0; i < 4; ++i)
        #pragma unroll
        for (int j = 0; j < 4; ++j)
            acc[i][j] = __builtin_amdgcn_mfma_f32_16x16x32_bf16(af[i], bfg[j], acc[i][j], 0, 0, 0);
}

// Double-buffered pipelined K-loop. 33280 bytes: 2x(A 8KB + B 8KB) + epi overlay.
#define SMEMP_DECL                                              \
    __shared__ __align__(16) char smem_[33280];                 \
    bfraw* A0buf = (bfraw*)smem_;                               \
    bfraw* B0buf = (bfraw*)(smem_ + 8192);                      \
    bfraw* A1buf = (bfraw*)(smem_ + 16384);                     \
    bfraw* B1buf = (bfraw*)(smem_ + 24576);

#define PIPE_DSTS                                               \
    bfraw* a0d  = A0buf + wid * 512;                            \
    bfraw* a0d2 = A0buf + 2048 + wid * 512;                     \
    bfraw* b0d  = B0buf + wid * 512;                            \
    bfraw* b0d2 = B0buf + 2048 + wid * 512;                     \
    bfraw* a1d  = A1buf + wid * 512;                            \
    bfraw* a1d2 = A1buf + 2048 + wid * 512;                     \
    bfraw* b1d  = B1buf + wid * 512;                            \
    bfraw* b1d2 = B1buf + 2048 + wid * 512;

#define KLOOP_PRE(Abase, Astr, Bbase, Bstr)                                    \
    const bfraw* pa0 = (Abase) + (size_t)(t >> 2) * (Astr) + (t & 3) * 8;      \
    const bfraw* pa1 = pa0 + (size_t)64 * (Astr);                              \
    const bfraw* pb0 = (Bbase) + (size_t)(t >> 2) * (Bstr) + (t & 3) * 8;      \
    const bfraw* pb1 = pb0 + (size_t)64 * (Bstr);

#define STAGE0                                                                 \
    do { gload_lds16(pa0, a0d); gload_lds16(pa1, a0d2);                        \
         gload_lds16(pb0, b0d); gload_lds16(pb1, b0d2);                        \
         pa0 += 32; pa1 += 32; pb0 += 32; pb1 += 32; } while (0)
#define STAGE1                                                                 \
    do { gload_lds16(pa0, a1d); gload_lds16(pa1, a1d2);                        \
         gload_lds16(pb0, b1d); gload_lds16(pb1, b1d2);                        \
         pa0 += 32; pa1 += 32; pb0 += 32; pb1 += 32; } while (0)

// NIT must be even (all call sites: K/32 ∈ {4,8,16,32}).
// barrier -> prefetch other buffer -> compute current: the vmcnt(0) drain at
// the NEXT barrier fires after a full mfma_step, hiding prefetch latency.
#define PIPE_LOOP(NIT, Abase, Astr, Bbase, Bstr)                               \
    {                                                                          \
        KLOOP_PRE(Abase, Astr, Bbase, Bstr)                                    \
        STAGE0;                                                                \
        for (int it = 0; it < (NIT); it += 2) {                                \
            __syncthreads();                                                   \
            if (it + 1 < (NIT)) STAGE1;                                        \
            mfma_step(A0buf, B0buf, acc, wm, wn, q, mi);                       \
            __syncthreads();                                                   \
            if (it + 2 < (NIT)) STAGE0;                                        \
            if (it + 1 < (NIT))                                                \
                mfma_step(A1buf, B1buf, acc, wm, wn, q, mi);                   \
        }                                                                      \
        __syncthreads();                                                       \
    }

__device__ __forceinline__ int epi_row(int p, int lr) {
    return (lr < 16) ? (p * 16 + lr) : (64 + p * 16 + (lr - 16));
}

// ------------- prep: ln (blocks 0..4095) + 3 weight transposes -------------
__global__ __launch_bounds__(256) void prep_kernel(const float* __restrict__ x,
                                                   const float* __restrict__ lnw,
                                                   const float* __restrict__ lnb,
                                                   const float* __restrict__ Wh,
                                                   const float* __restrict__ Wo,
                                                   const float* __restrict__ Wqk,
                                                   bfraw* __restrict__ normb,
                                                   bfraw* __restrict__ WhT,
                                                   bfraw* __restrict__ WoT,
                                                   bfraw* __restrict__ WqkT) {
    __shared__ float tile[32][33];
    int bid = blockIdx.x;
    int t = threadIdx.x;
    if (bid < 4096) {
        int row  = bid * 4 + (t >> 6);
        int lane = t & 63;
        const float* xr = x + (size_t)row * DIMD;
        float4 v0 = ((const float4*)xr)[lane];
        float4 v1 = ((const float4*)xr)[lane + 64];
        float s  = v0.x + v0.y + v0.z + v0.w + v1.x + v1.y + v1.z + v1.w;
        float ss = v0.x*v0.x + v0.y*v0.y + v0.z*v0.z + v0.w*v0.w
                 + v1.x*v1.x + v1.y*v1.y + v1.z*v1.z + v1.w*v1.w;
        #pragma unroll
        for (int off = 32; off; off >>= 1) {
            s  += __shfl_xor(s, off);
            ss += __shfl_xor(ss, off);
        }
        float mu  = s * (1.f / DIMD);
        float var = ss * (1.f / DIMD) - mu * mu;
        float inv = rsqrtf(var + 1e-5f);
        float4 w0 = ((const float4*)lnw)[lane],  w1 = ((const float4*)lnw)[lane + 64];
        float4 b0 = ((const float4*)lnb)[lane],  b1 = ((const float4*)lnb)[lane + 64];
        unsigned int o0 = pkbf((v0.x - mu) * inv * w0.x + b0.x,
                               (v0.y - mu) * inv * w0.y + b0.y);
        unsigned int o1 = pkbf((v0.z - mu) * inv * w0.z + b0.z,
                               (v0.w - mu) * inv * w0.w + b0.w);
        unsigned int o2 = pkbf((v1.x - mu) * inv * w1.x + b1.x,
                               (v1.y - mu) * inv * w1.y + b1.y);
        unsigned int o3 = pkbf((v1.z - mu) * inv * w1.z + b1.z,
                               (v1.w - mu) * inv * w1.w + b1.w);
        unsigned int* brow = (unsigned int*)(normb + (size_t)row * DIMD);
        ((uint2*)brow)[lane]      = make_uint2(o0, o1);
        ((uint2*)brow)[lane + 64] = make_uint2(o2, o3);
        return;
    }
    bid -= 4096;
    const float* in; bfraw* outp; int R, C, nx;
    if (bid < 1024)      { in = Wh;  outp = WhT;  R = DIMD; C = 2 * HIDD; nx = 64; }
    else if (bid < 1536) { bid -= 1024; in = Wo;  outp = WoT;  R = HIDD; C = DIMD; nx = 16; }
    else                 { bid -= 1536; in = Wqk; outp = WqkT; R = DIMD; C = QKD;  nx = 4; }
    int c0 = (bid % nx) * 32, r0 = (bid / nx) * 32;
    int tr = t >> 3, tc4 = (t & 7) * 4;
    float4 v = *(const float4*)&in[(size_t)(r0 + tr) * C + c0 + tc4];
    tile[tr][tc4 + 0] = v.x; tile[tr][tc4 + 1] = v.y;
    tile[tr][tc4 + 2] = v.z; tile[tr][tc4 + 3] = v.w;
    __syncthreads();
    ushort4 s;
    s.x = f2bf(tile[tc4 + 0][tr]);
    s.y = f2bf(tile[tc4 + 1][tr]);
    s.z = f2bf(tile[tc4 + 2][tr]);
    s.w = f2bf(tile[tc4 + 3][tr]);
    *(ushort4*)&outp[(size_t)(c0 + tr) * R + r0 + tc4] = s;
}

// ------------- merged h+qk GEMM over normb -------------
// blockIdx.x 0..7: v cols -> vT; 8..15: gate cols; 16: qk -> qq/lq/kk + lkT.
__global__ __launch_bounds__(256) void gemm_h(const bfraw* __restrict__ A,
                                              const bfraw* __restrict__ WhT,
                                              const bfraw* __restrict__ WqkT,
                                              const float* __restrict__ bias,
                                              const float* __restrict__ bqk,
                                              const float* __restrict__ gamma,
                                              const float* __restrict__ beta,
                                              bfraw* __restrict__ vT,
                                              bfraw* __restrict__ gate,
                                              bfraw* __restrict__ qq,
                                              bfraw* __restrict__ lq,
                                              bfraw* __restrict__ kk,
                                              bfraw* __restrict__ lkT) {
    SMEMP_DECL
    bfraw* epi2 = (bfraw*)smem_;
    float* epi = (float*)smem_;
    int t = threadIdx.x;
    int lane = t & 63, wid = t >> 6;
    int wm = wid >> 1, wn = wid & 1;
    int q = lane >> 4, mi = lane & 15;
    int row0 = blockIdx.y * 128, col0 = blockIdx.x * 128;
    bool is_qk = (blockIdx.x == 16);
    f32x4 acc[4][4] = {};
    PIPE_DSTS
    {
        const bfraw* Bbase = is_qk ? WqkT : (WhT + (size_t)col0 * DIMD);
        PIPE_LOOP(16, A + (size_t)row0 * DIMD, DIMD, Bbase, DIMD)
    }
    int bg = row0 >> 8;
    if (is_qk) {
        #pragma unroll
        for (int p = 0; p < 4; ++p) {
            #pragma unroll
            for (int j = 0; j < 4; ++j) {
                float bv = bqk[wn * 64 + j * 16 + mi];
                #pragma unroll
                for (int rg = 0; rg < 4; ++rg)
                    epi[(wm * 16 + q * 4 + rg) * EPIW + wn * 64 + j * 16 + mi] =
                        silu_f(acc[p][j][rg] + bv);
            }
            __syncthreads();
            {
                int lr = t >> 3, c0t = (t & 7) * 16;
                int gr = row0 + epi_row(p, lr);
                const float* src = &epi[lr * EPIW + c0t];
                float z[16];
                #pragma unroll
                for (int k = 0; k < 16; ++k) z[k] = src[k];
                #pragma unroll
                for (int hd = 0; hd < 3; ++hd) {        // 0:qq 1:lq 2:kk
                    bfraw* arr = (hd == 0) ? qq : (hd == 1) ? lq : kk;
                    const float* gp = gamma + hd * QKD + c0t;
                    const float* ep = beta  + hd * QKD + c0t;
                    float tmp[16];
                    #pragma unroll
                    for (int k = 0; k < 16; ++k) tmp[k] = z[k] * gp[k] + ep[k];
                    store16bf(arr + (size_t)gr * QKD + c0t, tmp);
                }
            }
            {
                int c = t >> 1, half = t & 1;
                float g3 = gamma[3 * QKD + c], e3 = beta[3 * QKD + c];
                int j0 = (row0 & 255) + half * 64 + p * 16;
                float tmp[16];
                #pragma unroll
                for (int k = 0; k < 16; ++k)
                    tmp[k] = epi[(half * 16 + k) * EPIW + c] * g3 + e3;
                store16bf(lkT + ((size_t)bg * QKD + c) * GRP + j0, tmp);
            }
            __syncthreads();
        }
        return;
    }
    // h paths: full-tile bf16 epilogue, stride EPB shorts.
    #pragma unroll
    for (int p = 0; p < 4; ++p)
        #pragma unroll
        for (int j = 0; j < 4; ++j) {
            float bv = bias[col0 + wn * 64 + j * 16 + mi];
            #pragma unroll
            for (int rg = 0; rg < 4; ++rg) {
                int rowl = wm * 64 + p * 16 + q * 4 + rg;
                epi2[rowl * EPB + wn * 64 + j * 16 + mi] = f2bf(silu_f(acc[p][j][rg] + bv));
            }
        }
    __syncthreads();
    if (col0 < HIDD) {
        // vT path: thread t -> word-col e2 = t&63, j-block t>>6.
        int e2 = t & 63, jblk = t >> 6;
        const unsigned int* ep32 = (const unsigned int*)epi2;   // EPB/2 = 65 words/row
        unsigned int wv[32];
        #pragma unroll
        for (int jj = 0; jj < 32; ++jj)
            wv[jj] = ep32[(size_t)(jblk * 32 + jj) * 65 + e2];
        int jbase = (row0 & 255) + jblk * 32;
        bfraw* dst0 = vT + ((size_t)bg * HIDD + col0 + 2 * e2) * GRP + jbase;
        bfraw* dst1 = dst0 + GRP;
        #pragma unroll
        for (int vq = 0; vq < 4; ++vq) {
            u16x8 s;
            #pragma unroll
            for (int k = 0; k < 8; ++k) s[k] = (bfraw)(wv[vq * 8 + k] & 0xffffu);
            *(u16x8*)(dst0 + vq * 8) = s;
        }
        #pragma unroll
        for (int vq = 0; vq < 4; ++vq) {
            u16x8 s;
            #pragma unroll
            for (int k = 0; k < 8; ++k) s[k] = (bfraw)(wv[vq * 8 + k] >> 16);
            *(u16x8*)(dst1 + vq * 8) = s;
        }
    } else {
        // gate path: row-major copy-out.
        int lr = t >> 1, seg = t & 1;
        const bfraw* src = epi2 + (size_t)lr * EPB + seg * 64;
        bfraw* dst = gate + (size_t)(row0 + lr) * HIDD + (col0 - HIDD) + seg * 64;
        #pragma unroll
        for (int vq = 0; vq < 8; ++vq)
            *(u16x8*)(dst + vq * 8) = *(const u16x8*)(src + vq * 8);
    }
}

// ------------- fused sim + kv dispatch.
// blocks 0..511: kv; blocks 512..703: sim.
__global__ __launch_bounds__(256) void simkv_kernel(const bfraw* __restrict__ qq,
                                                    const bfraw* __restrict__ kk,
                                                    bfraw* __restrict__ attn,
                                                    const bfraw* __restrict__ vT,
                                                    const bfraw* __restrict__ lkT,
                                                    bfraw* __restrict__ kvT_raw) {
    SMEMP_DECL
    float* epi = (float*)smem_;
    int t = threadIdx.x;
    int lane = t & 63, wid = t >> 6;
    int wm = wid >> 1, wn = wid & 1;
    int q = lane >> 4, mi = lane & 15;
    int bid = blockIdx.x;
    f32x4 acc[4][4] = {};
    PIPE_DSTS
    if (bid < 512) {
        // ---- kv: kvT_raw[bg][e][d] = sum_j vT[bg][e][j] * lkT[bg][d][j] ----
        int bg = bid >> 3;
        int row0 = (bid & 7) * 128;
        PIPE_LOOP(8, vT + (size_t)bg * HIDD * GRP + (size_t)row0 * GRP, GRP,
                  lkT + (size_t)bg * QKD * GRP, GRP)
        bfraw* outg = kvT_raw + (size_t)bg * HIDD * QKD;
        #pragma unroll
        for (int p = 0; p < 4; ++p) {
            #pragma unroll
            for (int j = 0; j < 4; ++j)
                #pragma unroll
                for (int rg = 0; rg < 4; ++rg)
                    epi[(wm * 16 + q * 4 + rg) * EPIW + wn * 64 + j * 16 + mi] = acc[p][j][rg];
            __syncthreads();
            int lr = t >> 3, c0t = (t & 7) * 16;
            int gr = row0 + epi_row(p, lr);
            store16bf(outg + (size_t)gr * QKD + c0t, &epi[lr * EPIW + c0t]);
            __syncthreads();
        }
        return;
    }
    // ---- sim: attn[bg][i][j] = mask * relu(qq_i . kk_j / G)^2 ----
    int i = bid - 512;
    int bg = i & 63;
    int tid = i >> 6;
    int ry = (tid == 0) ? 0 : 1;
    int rx = (tid == 2) ? 1 : 0;
    int row0 = ry * 128, col0 = rx * 128;
    PIPE_LOOP(4, qq + (size_t)(bg * GRP + row0) * QKD, QKD,
              kk + (size_t)(bg * GRP + col0) * QKD, QKD)
    bfraw* ag = attn + (size_t)bg * GRP * GRP;
    #pragma unroll
    for (int p = 0; p < 4; ++p) {
        #pragma unroll
        for (int j = 0; j < 4; ++j) {
            int colg = col0 + wn * 64 + j * 16 + mi;
            #pragma unroll
            for (int rg = 0; rg < 4; ++rg) {
                int rowg = row0 + wm * 64 + p * 16 + q * 4 + rg;
                float s = acc[p][j][rg] * (1.f / GRP);
                s = fmaxf(s, 0.f);
                s = s * s;
                epi[(wm * 16 + q * 4 + rg) * EPIW + wn * 64 + j * 16 + mi] =
                    (colg > rowg) ? 0.f : s;
            }
        }
        __syncthreads();
        int lr = t >> 3, c0t = (t & 7) * 16;
        int gr = row0 + epi_row(p, lr);
        store16bf(ag + (size_t)gr * GRP + col0 + c0t, &epi[lr * EPIW + c0t]);
        __syncthreads();
    }
}

// ------------- exclusive cumsum over groups (with /G) -------------
__global__ __launch_bounds__(256) void cumsum2_kernel(const bfraw* __restrict__ raw,
                                                      bfraw* __restrict__ ex) {
    int idx = blockIdx.x * 256 + threadIdx.x;
    int b = idx >> 17;
    int r = idx & 131071;
    const bfraw* rp = raw + (size_t)b * NGRP * 131072 + r;
    bfraw* ep = ex + (size_t)b * NGRP * 131072 + r;
    float run = 0.f;
    #pragma unroll
    for (int g = 0; g < NGRP; ++g) {
        ep[(size_t)g * 131072] = f2bf(run);
        run += bf2f(rp[(size_t)g * 131072]) * (1.f / GRP);
    }
}

// ------------- gated = gate .* (attn@vv + lq@kv_ex)  (bf16 out) -------------
__global__ __launch_bounds__(256) void quadlin_mfma(const bfraw* __restrict__ attn,
                                                    const bfraw* __restrict__ vT,
                                                    const bfraw* __restrict__ lq,
                                                    const bfraw* __restrict__ kvT_ex,
                                                    const bfraw* __restrict__ gate,
                                                    bfraw* __restrict__ gated) {
    int bg = blockIdx.z;
    int row0 = blockIdx.y * 128;
    int col0 = blockIdx.x * 128;
    SMEMP_DECL
    float* epi = (float*)smem_;
    int t = threadIdx.x;
    int lane = t & 63, wid = t >> 6;
    int wm = wid >> 1, wn = wid & 1;
    int q = lane >> 4, mi = lane & 15;
    f32x4 acc[4][4] = {};
    PIPE_DSTS
    // Part 1: quadratic. A = attn rows (stride 256), BT = vT rows (stride 256).
    {
        int nit = (row0 + 128) >> 5;     // causal: attn[i][j]=0 for j>i
        PIPE_LOOP(nit, attn + (size_t)bg * GRP * GRP + (size_t)row0 * GRP, GRP,
                  vT + (size_t)bg * HIDD * GRP + (size_t)col0 * GRP, GRP)
    }
    // Part 2: linear. A = lq rows (stride 128), BT = kvT_ex rows (stride 128).
    PIPE_LOOP(4, lq + (size_t)(bg * GRP + row0) * QKD, QKD,
              kvT_ex + (size_t)bg * HIDD * QKD + (size_t)col0 * QKD, QKD)
    #pragma unroll
    for (int p = 0; p < 4; ++p) {
        #pragma unroll
        for (int j = 0; j < 4; ++j)
            #pragma unroll
            for (int rg = 0; rg < 4; ++rg)
                epi[(wm * 16 + q * 4 + rg) * EPIW + wn * 64 + j * 16 + mi] = acc[p][j][rg];
        __syncthreads();
        int lr = t >> 3, c0t = (t & 7) * 16;
        int gr = row0 + epi_row(p, lr);          // group-local row
        size_t grow = (size_t)bg * GRP + gr;
        const float* src = &epi[lr * EPIW + c0t];
        const bfraw* gsrc = gate + grow * HIDD + col0 + c0t;
        u16x8 g0 = *(const u16x8*)gsrc;
        u16x8 g1 = *(const u16x8*)(gsrc + 8);
        float tmp[16];
        #pragma unroll
        for (int k = 0; k < 8; ++k) tmp[k] = src[k] * bf2f(g0[k]);
        #pragma unroll
        for (int k = 0; k < 8; ++k) tmp[8 + k] = src[8 + k] * bf2f(g1[k]);
        store16bf(gated + grow * HIDD + col0 + c0t, tmp);
        __syncthreads();
    }
}

// ------------- final: out = gated @ WoT^T + bo + x  (fp32 out) -------------
__global__ __launch_bounds__(256) void gemm_final(const bfraw* __restrict__ A,
                                                  const bfraw* __restrict__ BT,
                                                  const float* __restrict__ bo,
                                                  const float* __restrict__ x,
                                                  float* __restrict__ out) {
    SMEMP_DECL
    float* epi = (float*)smem_;
    int t = threadIdx.x;
    int lane = t & 63, wid = t >> 6;
    int wm = wid >> 1, wn = wid & 1;
    int q = lane >> 4, mi = lane & 15;
    int row0 = blockIdx.y * 128, col0 = blockIdx.x * 128;
    f32x4 acc[4][4] = {};
    PIPE_DSTS
    PIPE_LOOP(32, A + (size_t)row0 * HIDD, HIDD, BT + (size_t)col0 * HIDD, HIDD)
    #pragma unroll
    for (int p = 0; p < 4; ++p) {
        #pragma unroll
        for (int j = 0; j < 4; ++j) {
            float bv = bo[col0 + wn * 64 + j * 16 + mi];
            #pragma unroll
            for (int rg = 0; rg < 4; ++rg)
                epi[(wm * 16 + q * 4 + rg) * EPIW + wn * 64 + j * 16 + mi] =
                    acc[p][j][rg] + bv;
        }
        __syncthreads();
        int lr = t >> 3, c0t = (t & 7) * 16;
        int gr = row0 + epi_row(p, lr);
        const float* src = &epi[lr * EPIW + c0t];
        const float* xsrc = x + (size_t)gr * DIMD + col0 + c0t;
        float* dst = out + (size_t)gr * DIMD + col0 + c0t;
        #pragma unroll
        for (int v = 0; v < 4; ++v) {
            float4 a = ((const float4*)src)[v];
            float4 xv = ((const float4*)xsrc)[v];
            a.x += xv.x; a.y += xv.y; a.z += xv.z; a.w += xv.w;
            ((float4*)dst)[v] = a;
        }
        __syncthreads();
    }
}

extern "C" void kernel_launch(void* const* d_in, const int* in_sizes, int n_in,
                              void* d_out, int out_size, void* d_ws, size_t ws_size,
                              hipStream_t stream) {
    const float* x     = (const float*)d_in[0];
    const float* ln_w  = (const float*)d_in[1];
    const float* ln_b  = (const float*)d_in[2];
    const float* Wh    = (const float*)d_in[3];
    const float* bh    = (const float*)d_in[4];
    const float* Wqk   = (const float*)d_in[5];
    const float* bqk   = (const float*)d_in[6];
    const float* gamma = (const float*)d_in[7];
    const float* beta  = (const float*)d_in[8];
    const float* Wo    = (const float*)d_in[9];
    const float* bo    = (const float*)d_in[10];
    float* out = (float*)d_out;

    // d_out (32 MiB) hosts short-lived buffers; all dead before gemm_final writes out.
    char* outb_ = (char*)d_out;
    bfraw* attn = (bfraw*)(outb_);                    //  8 MiB [64][256][256]
    bfraw* qq   = (bfraw*)(outb_ + 8388608);          //  4 MiB [16384][128]
    bfraw* kk   = (bfraw*)(outb_ + 12582912);         //  4 MiB
    bfraw* lq   = (bfraw*)(outb_ + 16777216);         //  4 MiB
    bfraw* WhT  = (bfraw*)(outb_ + 20971520);         //  2 MiB [2048][512]
    bfraw* WqkT = (bfraw*)(outb_ + 23068672);         //  128 KiB [128][512]

    // ws layout (byte offsets):
    char* wsb = (char*)d_ws;
    bfraw* vT      = (bfraw*)(wsb);                   // 32 MiB [64][1024][256]
    bfraw* gate    = (bfraw*)(wsb + 33554432);        // 32 MiB [16384][1024]
    bfraw* gated   = (bfraw*)(wsb + 67108864);        // 32 MiB [16384][1024]
    bfraw* normb   = (bfraw*)(wsb + 100663296);       // 16 MiB [16384][512]
    bfraw* kvT_raw = (bfraw*)(wsb + 117440512);       // 16 MiB [64][1024][128]
    bfraw* kvT_ex  = (bfraw*)(wsb + 134217728);       // 16 MiB [64][1024][128]
    bfraw* lkT     = (bfraw*)(wsb + 150994944);       //  4 MiB [64][128][256]
    bfraw* WoT     = (bfraw*)(wsb + 155189248);       //  1 MiB [512][1024]

    // 1. prep: LayerNorm + all weight transposes (one dispatch)
    prep_kernel<<<4096 + 1024 + 512 + 64, 256, 0, stream>>>(
        x, ln_w, ln_b, Wh, Wo, Wqk, normb, WhT, WoT, WqkT);
    // 2. merged h+qk GEMM: vT + gate + qq/lq/kk/lkT  (17 column tiles)
    gemm_h<<<dim3(17, TROWS / 128), 256, 0, stream>>>(
        normb, WhT, WqkT, bh, bqk, gamma, beta, vT, gate, qq, lq, kk, lkT);
    // 3. fused kv + sim (one dispatch; kv blocks first)
    simkv_kernel<<<512 + 192, 256, 0, stream>>>(qq, kk, attn, vT, lkT, kvT_raw);
    // 4. exclusive cumsum over groups (with /G) -> kvT_ex
    cumsum2_kernel<<<(BATCH * QKD * HIDD) / 256, 256, 0, stream>>>(kvT_raw, kvT_ex);
    // 5. gated = gate .* (attn@vv + lq@kv_ex)
    quadlin_mfma<<<dim3(HIDD / 128, GRP / 128, BGRP), 256, 0, stream>>>(
        attn, vT, lq, kvT_ex, gate, gated);
    // 6. out = gated @ Wo + bo + x
    gemm_final<<<dim3(DIMD / 128, TROWS / 128), 256, 0, stream>>>(gated, WoT, bo, x, out);
}